// Round 1
// 1072.291 us; speedup vs baseline: 1.1458x; 1.1458x over previous
//
#include <hip/hip_runtime.h>
#include <cstdint>

// ---------------------------------------------------------------------------
// ChartParser: span scores + per-batch CKY DP + backtrack.
// B=64, S=256, D=H=1024. Output: int32 [2][B][S] (lefts then rights).
// Round 9: CKY restructured to ONE barrier per diagonal:
//  - cross-group reduce of diag w-1 merged into the partial phase of diag w.
//    Only the extreme split candidates (len 0 / len w-1) of diag w touch diag
//    w-1; they are rerouted through pvF/pvL written by the reducing lane.
//    Group m-loop covers middle lengths [1, w-2] only (reads diags <= w-2).
//    pv/pmv/pvF/pvL double-buffered.
//  - in-loop __syncthreads() (which force-drains vmcnt(0) = HBM store RT for
//    the per-step SP global store) replaced by raw "s_waitcnt lgkmcnt(0);
//    s_barrier"; a single vmcnt(0) drain before backtrack gives visibility.
//  Candidate order stays strictly ascending in m with strict '>' => exact
//  jnp.argmax first-max semantics preserved.
// ---------------------------------------------------------------------------

#define Bb 64
#define Ss 256
#define Dd 1024
#define Hh 1024

typedef __attribute__((ext_vector_type(8))) _Float16 f16x8;
typedef __attribute__((ext_vector_type(4))) float f32x4;

// x = h + l + delta, |delta| <= 2^-22 |x| (fp16 RNE twice)
__device__ __forceinline__ void split2(float x, unsigned short& h,
                                       unsigned short& l) {
  _Float16 hh = (_Float16)x;
  _Float16 ll = (_Float16)(x - (float)hh);
  h = __builtin_bit_cast(unsigned short, hh);
  l = __builtin_bit_cast(unsigned short, ll);
}

// ---------------------------------------------------------------------------
// Weight split+transpose: W fp32 [1024 k-rows, ld ldw] -> O fp16 [n][k],
// limb planes at +0, +plane.
// ---------------------------------------------------------------------------
__global__ __launch_bounds__(256) void splitw_kernel(
    const float* __restrict__ W, int ldw, unsigned short* __restrict__ O,
    long long plane) {
  int idx = blockIdx.x * 256 + threadIdx.x;  // n*1024 + k
  int n = idx >> 10, k = idx & 1023;
  float x = W[(long long)k * ldw + n];
  unsigned short h, l;
  split2(x, h, l);
  O[idx] = h;
  O[plane + idx] = l;
}

// Extract Wbil's bias row / col / corner.
__global__ __launch_bounds__(256) void bilvec_kernel(
    const float* __restrict__ Wbil, float* __restrict__ brow,
    float* __restrict__ bcol, float* __restrict__ corner) {
  int i = blockIdx.x * 256 + threadIdx.x;  // 0..1023
  brow[i] = Wbil[1024 * 1025 + i];
  bcol[i] = Wbil[i * 1025 + 1024];
  if (i == 0) corner[0] = Wbil[1024 * 1025 + 1024];
}

__device__ __forceinline__ void pack8(char* dst, const unsigned short* v) {
  uint4 u;
  u.x = (unsigned)v[0] | ((unsigned)v[1] << 16);
  u.y = (unsigned)v[2] | ((unsigned)v[3] << 16);
  u.z = (unsigned)v[4] | ((unsigned)v[5] << 16);
  u.w = (unsigned)v[6] | ((unsigned)v[7] << 16);
  *(uint4*)dst = u;
}

// split 16 fp32 -> 2x16 fp16 limbs, store (swizzled) to 2 LDS planes
__device__ __forceinline__ void split_store16f(const float* xs, char* lds,
                                               int base, int wa0, int wa1) {
  unsigned short hs[16], ls[16];
#pragma unroll
  for (int i = 0; i < 16; ++i) split2(xs[i], hs[i], ls[i]);
  pack8(&lds[base + wa0], hs);
  pack8(&lds[base + wa1], hs + 8);
  pack8(&lds[base + 8192 + wa0], ls);
  pack8(&lds[base + 8192 + wa1], ls + 8);
}

// 4-product accumulate for one nf column: (ah+al)x(bh+bl), all kept
#define MFMA4(afv, bh, blv, accs, nf)                                        \
  {                                                                          \
    _Pragma("unroll") for (int mf = 0; mf < 4; ++mf) accs[mf][nf] =          \
        __builtin_amdgcn_mfma_f32_16x16x32_f16(afv[0][mf], bh,               \
                                               accs[mf][nf], 0, 0, 0);       \
    _Pragma("unroll") for (int mf = 0; mf < 4; ++mf) accs[mf][nf] =          \
        __builtin_amdgcn_mfma_f32_16x16x32_f16(afv[0][mf], blv,              \
                                               accs[mf][nf], 0, 0, 0);       \
    _Pragma("unroll") for (int mf = 0; mf < 4; ++mf) accs[mf][nf] =          \
        __builtin_amdgcn_mfma_f32_16x16x32_f16(afv[1][mf], bh,               \
                                               accs[mf][nf], 0, 0, 0);       \
    _Pragma("unroll") for (int mf = 0; mf < 4; ++mf) accs[mf][nf] =          \
        __builtin_amdgcn_mfma_f32_16x16x32_f16(afv[1][mf], blv,              \
                                               accs[mf][nf], 0, 0, 0);       \
  }

// ---------------------------------------------------------------------------
// MFMA GEMM (NN): out = act(A[M,1024]_fp32 * Bsp + bias). Bsp pre-split fp16
// [n][k], limb planes at stride bplane. Tile 128x128, BK=32, 256 threads,
// wave-tile 64x64 (4x4 frags of mfma_f32_16x16x32_f16). LDS 32KB:
// Ah@0, Al@8192, Bh@16384, Bl@24576; 16B-chunk XOR swizzle
// phi(r)=((r>>1)^(r>>3))&3 (proven conflict-clean, rounds 5-7).
// If n0 >= 1024 the block writes C1/bias1 at col-1024 (fused dual output).
// ---------------------------------------------------------------------------
template <bool LEAKY>
__global__ __launch_bounds__(256, 3) void gemm_mfma_kernel(
    const float* __restrict__ A, const unsigned short* __restrict__ Bsp,
    long long bplane, float* __restrict__ C0, float* __restrict__ C1,
    const float* __restrict__ bias0, const float* __restrict__ bias1) {
  const int m0 = blockIdx.y * 128;
  const int n0 = blockIdx.x * 128;
  __shared__ __align__(16) char lds[32768];
  const int t = threadIdx.x;
  const int L = t & 63, w = t >> 6, q = L >> 4, l15 = L & 15;

  const int ar = t >> 1, ah = t & 1;
  const float* aptr = A + (long long)(m0 + ar) * 1024 + ah * 16;
  const int phiA = ((ar >> 1) ^ (ar >> 3)) & 3;
  const int wa0 = ar * 64 + (((2 * ah + 0) ^ phiA) << 4);
  const int wa1 = ar * 64 + (((2 * ah + 1) ^ phiA) << 4);

  int offA0[4], offB0[4];
#pragma unroll
  for (int f = 0; f < 4; ++f) {
    int rowa = ((w & 1) << 6) + (f << 4) + l15;
    offA0[f] = rowa * 64 + ((q ^ (((rowa >> 1) ^ (rowa >> 3)) & 3)) << 4);
    int rowb = ((w >> 1) << 6) + (f << 4) + l15;
    offB0[f] =
        16384 + rowb * 64 + ((q ^ (((rowb >> 1) ^ (rowb >> 3)) & 3)) << 4);
  }

  f32x4 acc[4][4];
#pragma unroll
  for (int i = 0; i < 4; ++i)
#pragma unroll
    for (int j = 0; j < 4; ++j) acc[i][j] = (f32x4){0.f, 0.f, 0.f, 0.f};

  for (int k0 = 0; k0 < 1024; k0 += 32) {
    // B staging: 4 x 16B per thread (pre-split fp16, swizzled dest)
#pragma unroll
    for (int j = 0; j < 4; ++j) {
      int fc = t + (j << 8);  // 0..1023
      int s = fc >> 9, r = (fc >> 2) & 127, sc = fc & 3;
      const unsigned short* bs = Bsp + s * bplane;
      uint4 bv =
          *(const uint4*)(bs + (long long)(n0 + r) * 1024 + k0 + (sc << 3));
      int phi = ((r >> 1) ^ (r >> 3)) & 3;
      *(uint4*)&lds[16384 + s * 8192 + r * 64 + ((sc ^ phi) << 4)] = bv;
    }
    // A staging: 16 fp32 -> 2 x 16 fp16 limbs
    {
      float4 a0 = *(const float4*)(aptr + k0);
      float4 a1 = *(const float4*)(aptr + k0 + 4);
      float4 a2 = *(const float4*)(aptr + k0 + 8);
      float4 a3 = *(const float4*)(aptr + k0 + 12);
      float xs[16] = {a0.x, a0.y, a0.z, a0.w, a1.x, a1.y, a1.z, a1.w,
                      a2.x, a2.y, a2.z, a2.w, a3.x, a3.y, a3.z, a3.w};
      split_store16f(xs, lds, 0, wa0, wa1);
    }
    __syncthreads();
    f16x8 af[2][4];
#pragma unroll
    for (int s = 0; s < 2; ++s)
#pragma unroll
      for (int f = 0; f < 4; ++f)
        af[s][f] = *(const f16x8*)&lds[s * 8192 + offA0[f]];
#pragma unroll
    for (int nf = 0; nf < 4; ++nf) {
      f16x8 bh = *(const f16x8*)&lds[offB0[nf]];
      f16x8 bl = *(const f16x8*)&lds[8192 + offB0[nf]];
      MFMA4(af, bh, bl, acc, nf);
    }
    __syncthreads();
  }

  const bool isR = (n0 >= 1024);
  float* Co = isR ? C1 : C0;
  const float* bp = isR ? bias1 : bias0;
  const int nc0 = n0 & 1023;
#pragma unroll
  for (int nf = 0; nf < 4; ++nf) {
    int col = nc0 + ((w >> 1) << 6) + (nf << 4) + l15;
    float bz = bp[col];
#pragma unroll
    for (int mf = 0; mf < 4; ++mf) {
#pragma unroll
      for (int r = 0; r < 4; ++r) {
        int row = m0 + ((w & 1) << 6) + (mf << 4) + (q << 2) + r;
        float x = acc[mf][nf][r] + bz;
        if (LEAKY) x = (x > 0.f) ? x : 0.1f * x;
        Co[(long long)row * 1024 + col] = x;
      }
    }
  }
}

// ---------------------------------------------------------------------------
// Batched NT GEMM on MFMA: C[b] = tmpA[b] * rights[b]^T + rowAdd + scal.
// Both operands fp32, split in-kernel to fp16x2. Tile 128x128, grid (2,2,64).
// ---------------------------------------------------------------------------
__global__ __launch_bounds__(256, 3) void gemmnt_mfma_kernel(
    const float* __restrict__ A, const float* __restrict__ B,
    float* __restrict__ C, const float* __restrict__ rowAdd,
    const float* __restrict__ scal) {
  const int bz = blockIdx.z;
  A += (long long)bz * 256 * 1024;
  B += (long long)bz * 256 * 1024;
  C += (long long)bz * 256 * 256;
  const int m0 = blockIdx.y * 128;
  const int n0 = blockIdx.x * 128;
  __shared__ __align__(16) char lds[32768];
  const int t = threadIdx.x;
  const int L = t & 63, w = t >> 6, q = L >> 4, l15 = L & 15;

  const int ar = t >> 1, ah = t & 1;
  const float* aptr = A + (long long)(m0 + ar) * 1024 + ah * 16;
  const float* bptr = B + (long long)(n0 + ar) * 1024 + ah * 16;
  const int phiA = ((ar >> 1) ^ (ar >> 3)) & 3;
  const int wa0 = ar * 64 + (((2 * ah + 0) ^ phiA) << 4);
  const int wa1 = ar * 64 + (((2 * ah + 1) ^ phiA) << 4);

  int offA0[4], offB0[4];
#pragma unroll
  for (int f = 0; f < 4; ++f) {
    int rowa = ((w & 1) << 6) + (f << 4) + l15;
    offA0[f] = rowa * 64 + ((q ^ (((rowa >> 1) ^ (rowa >> 3)) & 3)) << 4);
    int rowb = ((w >> 1) << 6) + (f << 4) + l15;
    offB0[f] =
        16384 + rowb * 64 + ((q ^ (((rowb >> 1) ^ (rowb >> 3)) & 3)) << 4);
  }

  f32x4 acc[4][4];
#pragma unroll
  for (int i = 0; i < 4; ++i)
#pragma unroll
    for (int j = 0; j < 4; ++j) acc[i][j] = (f32x4){0.f, 0.f, 0.f, 0.f};

  for (int k0 = 0; k0 < 1024; k0 += 32) {
    {
      float4 a0 = *(const float4*)(aptr + k0);
      float4 a1 = *(const float4*)(aptr + k0 + 4);
      float4 a2 = *(const float4*)(aptr + k0 + 8);
      float4 a3 = *(const float4*)(aptr + k0 + 12);
      float xs[16] = {a0.x, a0.y, a0.z, a0.w, a1.x, a1.y, a1.z, a1.w,
                      a2.x, a2.y, a2.z, a2.w, a3.x, a3.y, a3.z, a3.w};
      split_store16f(xs, lds, 0, wa0, wa1);
      float4 b0 = *(const float4*)(bptr + k0);
      float4 b1 = *(const float4*)(bptr + k0 + 4);
      float4 b2 = *(const float4*)(bptr + k0 + 8);
      float4 b3 = *(const float4*)(bptr + k0 + 12);
      float ys[16] = {b0.x, b0.y, b0.z, b0.w, b1.x, b1.y, b1.z, b1.w,
                      b2.x, b2.y, b2.z, b2.w, b3.x, b3.y, b3.z, b3.w};
      split_store16f(ys, lds, 16384, wa0, wa1);
    }
    __syncthreads();
    f16x8 af[2][4];
#pragma unroll
    for (int s = 0; s < 2; ++s)
#pragma unroll
      for (int f = 0; f < 4; ++f)
        af[s][f] = *(const f16x8*)&lds[s * 8192 + offA0[f]];
#pragma unroll
    for (int nf = 0; nf < 4; ++nf) {
      f16x8 bh = *(const f16x8*)&lds[offB0[nf]];
      f16x8 bl = *(const f16x8*)&lds[8192 + offB0[nf]];
      MFMA4(af, bh, bl, acc, nf);
    }
    __syncthreads();
  }

  const float sc_add = scal[0];
#pragma unroll
  for (int mf = 0; mf < 4; ++mf) {
#pragma unroll
    for (int r = 0; r < 4; ++r) {
      int row = m0 + ((w & 1) << 6) + (mf << 4) + (q << 2) + r;
      float radd = sc_add + rowAdd[(long long)bz * 256 + row];
#pragma unroll
      for (int nf = 0; nf < 4; ++nf) {
        int col = n0 + ((w >> 1) << 6) + (nf << 4) + l15;
        C[(long long)row * 256 + col] = acc[mf][nf][r] + radd;
      }
    }
  }
}

// ---------------------------------------------------------------------------
// tmpb[i] = dot(lefts[i,:], Wbil[0:H, H]) + Wbil[H,H].  One wave per row.
// ---------------------------------------------------------------------------
__global__ __launch_bounds__(64) void colvec_kernel(
    const float* __restrict__ lefts, const float* __restrict__ bcol,
    const float* __restrict__ corner, float* __restrict__ tmpb) {
  int row = blockIdx.x;
  int lane = threadIdx.x;
  const float* a = lefts + (long long)row * Hh;
  float s = 0.f;
#pragma unroll
  for (int h = lane; h < Hh; h += 64) s = fmaf(a[h], bcol[h], s);
#pragma unroll
  for (int off = 32; off > 0; off >>= 1) s += __shfl_down(s, off, 64);
  if (lane == 0) tmpb[row] = s + corner[0];
}

// ---------------------------------------------------------------------------
// CKY + backtrack. One block per batch, 1024 threads. Chart in LDS, packed
// triangular diag-major. ONE barrier per diagonal:
//   step w phase = { (a) finalize diag w-1 from last step's partials
//                    (pvF=len-0, group slots ascending, pvL=len-(w-2)),
//                    write Dch/SP, feed pvF/pvL of diag w;
//                    (b) group partials for diag w over MIDDLE lengths
//                    [1, w-2] only (reads Dch diags <= w-2); }
//   then "s_waitcnt lgkmcnt(0); s_barrier" (no vmcnt drain: SP global stores
//   float; drained once before backtrack).
// Partial buffers double-buffered (pb = w&1). Lane pairing (u, u+delta) for
// ds_read2 kept from round 8; m-ordering strictly ascending with strict '>'
// everywhere => exact first-max (jnp.argmax) semantics.
// Waves 0-3 also run (a), so they take the clipped tail m-ranges
// (g = G-1 - wave-group) for balance.
// ---------------------------------------------------------------------------
__global__ __launch_bounds__(1024) void cky_kernel(
    const float* __restrict__ scores,  // [64][256][256]
    uint8_t* __restrict__ Sws,         // [64][32896] packed triangular
    int* __restrict__ out)             // [2][64][256] int32
{
  const int b = blockIdx.x;
  const int t = threadIdx.x;
  const int n = Ss;
  const float* sc = scores + (long long)b * n * n;
  uint8_t* SP = Sws + (long long)b * 32896;

  __shared__ float Dch[32896];
  __shared__ float pv[2][2048];
  __shared__ uint8_t pmv[2][2048];
  __shared__ float pvF[2][256];
  __shared__ float pvL[2][256];
  __shared__ int stk[256];

  if (t < n) {
    out[b * n + t] = 0;
    out[Bb * n + b * n + t] = 0;
    // diag-0 "values" (all 0) as extreme candidates for diag 1 (buffer 1)
    pvF[1][t] = 0.f;
    pvL[1][t] = 0.f;
  }
  // No initial barrier needed: first reader of pvF/pvL[1] is (a) at w=2,
  // which is separated from this init by the w=1 end-of-step barrier.

  float scA = 0.f;                                      // score(diag w-1)
  float scP = (t < n - 1) ? sc[t * (n + 1) + 1] : 0.f;  // score(diag w)

  for (int w = 1; w < n; ++w) {
    const int nv = n - w;
    int lgT, delta, lgS;
    if (nv > 128) {        // R1: T=128, G=8, pair (u, u+128)
      lgT = 7; delta = 128; lgS = 8;
    } else if (nv > 64) {  // R2: T=64, G=16, pair (u, u+64)
      lgT = 6; delta = 64; lgS = 7;
    } else {               // R3: T=64, G=16, single
      lgT = 6; delta = 0; lgS = 7;
    }
    const int G = 1024 >> lgT;
    const int g = (G - 1) - (t >> lgT);  // reversed: waves 0-3 get tail
    const int u = t & ((1 << lgT) - 1);
    const int pb = w & 1, po = pb ^ 1;

    // prefetch score for diag w+1 (consumed by (a) at step w+2)
    float scNew = 0.f;
    if (w + 1 < n && t < n - w - 1) scNew = sc[t * (n + 1) + (w + 1)];

    // ---- (a): finalize diag v = w-1 from last step's partials ----
    if (w >= 2) {
      const int v = w - 1;
      const int nvv = nv + 1;  // cells in diag v
      const int lgSp = (nvv > 128) ? 8 : 7;
      const int Gp = (nvv > 128) ? 8 : 16;
      if (t < nvv) {
        float bb = pvF[po][t];  // candidate length 0
        int bm = 0;
#pragma unroll 4
        for (int g2 = 0; g2 < Gp; ++g2) {  // middle lengths, ascending
          float x = pv[po][(g2 << lgSp) + t];
          if (x > bb) { bb = x; bm = pmv[po][(g2 << lgSp) + t]; }
        }
        float xl = pvL[po][t];  // candidate length v-1
        if (xl > bb) { bb = xl; bm = v - 1; }
        float VAL = scA + bb;
        int offv = v * n - ((v * (v - 1)) >> 1);
        Dch[offv + t] = VAL;
        SP[offv + t] = (uint8_t)bm;
        // feed extreme candidates of diag w:
        if (t >= 1) pvF[pb][t - 1] = VAL;       // len 0 for cell t-1
        if (t < nvv - 1) pvL[pb][t] = VAL;      // len w-1 for cell t
      }
    }
    scA = scP;
    scP = scNew;

    // ---- (b): group partials for diag w, middle lengths [1, w-2] ----
    const int wGp = (w + G - 3) >> (10 - lgT);  // ceil((w-2)/G), >=0
    const int ml = 1 + g * wGp;
    const int mh = (w - 1 < ml + wGp) ? (w - 1) : (ml + wGp);
    float b0 = -3.0e38f, b1 = -3.0e38f;
    int m0i = 1, m1i = 1;
    if (u < nv && ml < mh) {
      int al = ml * n - ((ml * (ml - 1)) >> 1) + u;
      const int kr = w - 1 - ml;
      int ar = kr * n - ((kr * (kr - 1)) >> 1) + u + ml + 1;
      int dl = n - ml;
      int dr = n - w + ml + 1;
      if (delta) {
#pragma unroll 2
        for (int m = ml; m < mh; ++m) {
          float l0 = Dch[al], l1 = Dch[al + delta];   // -> ds_read2_b32
          float r0 = Dch[ar], r1 = Dch[ar + delta];   // -> ds_read2_b32
          float c0 = l0 + r0, c1 = l1 + r1;
          if (c0 > b0) { b0 = c0; m0i = m; }  // strict > = first max
          if (c1 > b1) { b1 = c1; m1i = m; }
          al += dl;
          ar -= dr;
          --dl;
          ++dr;
        }
      } else {
#pragma unroll 4
        for (int m = ml; m < mh; ++m) {
          float c = Dch[al] + Dch[ar];
          if (c > b0) { b0 = c; m0i = m; }
          al += dl;
          ar -= dr;
          --dl;
          ++dr;
        }
      }
    }
    pv[pb][(g << lgS) + u] = b0;
    pmv[pb][(g << lgS) + u] = (uint8_t)m0i;
    if (delta) {
      pv[pb][(g << lgS) + u + delta] = b1;
      pmv[pb][(g << lgS) + u + delta] = (uint8_t)m1i;
    }
    // LDS-ordering barrier only; SP global stores stay in flight.
    asm volatile("s_waitcnt lgkmcnt(0)\n\ts_barrier" ::: "memory");
  }

  // final (a): diag 255 (single cell; partials in buffer pb(255)=1, R3 layout)
  if (t == 0) {
    const int v = n - 1;
    float bb = pvF[1][0];
    int bm = 0;
#pragma unroll 4
    for (int g2 = 0; g2 < 16; ++g2) {
      float x = pv[1][g2 << 7];
      if (x > bb) { bb = x; bm = pmv[1][g2 << 7]; }
    }
    float xl = pvL[1][0];
    if (xl > bb) { bb = xl; bm = v - 1; }
    int offv = v * n - ((v * (v - 1)) >> 1);
    SP[offv] = (uint8_t)bm;
  }

  // Drain all SP stores (whole loop's worth) once, then barrier.
  asm volatile("s_waitcnt vmcnt(0) lgkmcnt(0)\n\ts_barrier" ::: "memory");
  uint8_t* spl = (uint8_t*)Dch;
  for (int idx = t; idx < 32896; idx += 1024) spl[idx] = SP[idx];
  asm volatile("s_waitcnt vmcnt(0) lgkmcnt(0)\n\ts_barrier" ::: "memory");
  if (t == 0) {
    int top = 0;
    stk[top++] = (0 << 16) | (n - 1);
    int cnt = 0;
    for (int step = 0; step < n - 1; ++step) {
      if (top > 0) {
        int ij = stk[--top];
        int ii = ij >> 16, jj = ij & 0xffff;
        out[b * n + cnt] = ii;
        out[Bb * n + b * n + cnt] = jj;
        ++cnt;
        int k = jj - ii;
        int s = ii + (int)spl[k * n - ((k * (k - 1)) >> 1) + ii];
        stk[top] = (ii << 16) | s;
        if (s > ii) ++top;
        stk[top] = ((s + 1) << 16) | jj;
        if (jj > s + 1) ++top;
      }
    }
  }
}

// ---------------------------------------------------------------------------
// Launch
// ---------------------------------------------------------------------------
extern "C" void kernel_launch(void* const* d_in, const int* in_sizes, int n_in,
                              void* d_out, int out_size, void* d_ws,
                              size_t ws_size, hipStream_t stream) {
  const float* X = (const float*)d_in[0];     // [64,256,1024]
  const float* Wl = (const float*)d_in[2];    // [1024,1024]
  const float* bl = (const float*)d_in[3];    // [1024]
  const float* Wr = (const float*)d_in[4];
  const float* br = (const float*)d_in[5];
  const float* Wbil = (const float*)d_in[6];  // [1025,1025]
  const float* bbil = (const float*)d_in[7];  // scalar
  int* out = (int*)d_out;

  // workspace layout
  float* ws = (float*)d_ws;
  float* lefts = ws;                          // 16777216 f
  float* rights = lefts + 16777216;           // 16777216 f
  float* tmpA = rights + 16777216;            // 16777216 f
  float* scoresP = tmpA + 16777216;           // 4194304 f
  float* tmpb = scoresP + 4194304;            // 16384 f
  float* browp = tmpb + 16384;                // 1024 f
  float* bcolp = browp + 1024;                // 1024 f
  float* cornerp = bcolp + 1024;              // 4 f
  unsigned short* Wlrt = (unsigned short*)(cornerp + 4);  // 2 x 2M fp16
  unsigned short* Wct = Wlrt + 2LL * 2097152;             // 2 x 1M fp16
  uint8_t* SPp = (uint8_t*)(Wct + 2LL * 1048576);         // 64x32896 u8

  // weight splits (+ Wbil bias vectors)
  splitw_kernel<<<dim3(4096), 256, 0, stream>>>(Wl, 1024, Wlrt, 2097152);
  splitw_kernel<<<dim3(4096), 256, 0, stream>>>(Wr, 1024, Wlrt + 1048576,
                                                2097152);
  splitw_kernel<<<dim3(4096), 256, 0, stream>>>(Wbil, 1025, Wct, 1048576);
  bilvec_kernel<<<dim3(4), 256, 0, stream>>>(Wbil, browp, bcolp, cornerp);

  // fused lefts|rights GEMM: N=2048
  dim3 gLR(16, 128);
  gemm_mfma_kernel<true><<<gLR, 256, 0, stream>>>(X, Wlrt, 2097152LL, lefts,
                                                  rights, bl, br);

  colvec_kernel<<<dim3(16384), 64, 0, stream>>>(lefts, bcolp, cornerp, tmpb);

  dim3 gA(8, 128);
  gemm_mfma_kernel<false><<<gA, 256, 0, stream>>>(lefts, Wct, 1048576LL, tmpA,
                                                  tmpA, browp, browp);

  dim3 g3(2, 2, 64);
  gemmnt_mfma_kernel<<<g3, 256, 0, stream>>>(tmpA, rights, scoresP, tmpb,
                                             bbil);

  cky_kernel<<<dim3(Bb), dim3(1024), 0, stream>>>(scoresP, SPp, out);
}

// Round 2
// 1029.341 us; speedup vs baseline: 1.1936x; 1.0417x over previous
//
#include <hip/hip_runtime.h>
#include <cstdint>

// ---------------------------------------------------------------------------
// ChartParser: span scores + per-batch CKY DP + backtrack.
// B=64, S=256, D=H=1024. Output: int32 [2][B][S] (lefts then rights).
// Round 10: CKY processes TWO diagonals per barrier (127 barriers vs 255):
//  phase = { (a) finalize diag w1=2s AND w2=2s+1 (w2's m=0 candidate =
//            VAL_w1(t+1) via __shfl_down(1); lane 63 recomputes it with a
//            bit-identical duplicate reduce); extremes read Dch directly;
//            (b) group partials for diags w1+2, w2+3 over MIDDLE lengths
//            only (w1': m in [2,w1'-3], w2': m in [3,w2'-4]) -> reads
//            diags <= 2s-1, all >= 1 barrier old. }
//  Thread groups split half/half between the two diags in (b); partial
//  double-buffered by superstep parity. Strictly-ascending-m evaluation with
//  strict '>' everywhere => exact jnp.argmax first-max semantics.
// ---------------------------------------------------------------------------

#define Bb 64
#define Ss 256
#define Dd 1024
#define Hh 1024

typedef __attribute__((ext_vector_type(8))) _Float16 f16x8;
typedef __attribute__((ext_vector_type(4))) float f32x4;

// x = h + l + delta, |delta| <= 2^-22 |x| (fp16 RNE twice)
__device__ __forceinline__ void split2(float x, unsigned short& h,
                                       unsigned short& l) {
  _Float16 hh = (_Float16)x;
  _Float16 ll = (_Float16)(x - (float)hh);
  h = __builtin_bit_cast(unsigned short, hh);
  l = __builtin_bit_cast(unsigned short, ll);
}

// ---------------------------------------------------------------------------
// Weight split+transpose: W fp32 [1024 k-rows, ld ldw] -> O fp16 [n][k],
// limb planes at +0, +plane.
// ---------------------------------------------------------------------------
__global__ __launch_bounds__(256) void splitw_kernel(
    const float* __restrict__ W, int ldw, unsigned short* __restrict__ O,
    long long plane) {
  int idx = blockIdx.x * 256 + threadIdx.x;  // n*1024 + k
  int n = idx >> 10, k = idx & 1023;
  float x = W[(long long)k * ldw + n];
  unsigned short h, l;
  split2(x, h, l);
  O[idx] = h;
  O[plane + idx] = l;
}

// Extract Wbil's bias row / col / corner.
__global__ __launch_bounds__(256) void bilvec_kernel(
    const float* __restrict__ Wbil, float* __restrict__ brow,
    float* __restrict__ bcol, float* __restrict__ corner) {
  int i = blockIdx.x * 256 + threadIdx.x;  // 0..1023
  brow[i] = Wbil[1024 * 1025 + i];
  bcol[i] = Wbil[i * 1025 + 1024];
  if (i == 0) corner[0] = Wbil[1024 * 1025 + 1024];
}

__device__ __forceinline__ void pack8(char* dst, const unsigned short* v) {
  uint4 u;
  u.x = (unsigned)v[0] | ((unsigned)v[1] << 16);
  u.y = (unsigned)v[2] | ((unsigned)v[3] << 16);
  u.z = (unsigned)v[4] | ((unsigned)v[5] << 16);
  u.w = (unsigned)v[6] | ((unsigned)v[7] << 16);
  *(uint4*)dst = u;
}

// split 16 fp32 -> 2x16 fp16 limbs, store (swizzled) to 2 LDS planes
__device__ __forceinline__ void split_store16f(const float* xs, char* lds,
                                               int base, int wa0, int wa1) {
  unsigned short hs[16], ls[16];
#pragma unroll
  for (int i = 0; i < 16; ++i) split2(xs[i], hs[i], ls[i]);
  pack8(&lds[base + wa0], hs);
  pack8(&lds[base + wa1], hs + 8);
  pack8(&lds[base + 8192 + wa0], ls);
  pack8(&lds[base + 8192 + wa1], ls + 8);
}

// 4-product accumulate for one nf column: (ah+al)x(bh+bl), all kept
#define MFMA4(afv, bh, blv, accs, nf)                                        \
  {                                                                          \
    _Pragma("unroll") for (int mf = 0; mf < 4; ++mf) accs[mf][nf] =          \
        __builtin_amdgcn_mfma_f32_16x16x32_f16(afv[0][mf], bh,               \
                                               accs[mf][nf], 0, 0, 0);       \
    _Pragma("unroll") for (int mf = 0; mf < 4; ++mf) accs[mf][nf] =          \
        __builtin_amdgcn_mfma_f32_16x16x32_f16(afv[0][mf], blv,              \
                                               accs[mf][nf], 0, 0, 0);       \
    _Pragma("unroll") for (int mf = 0; mf < 4; ++mf) accs[mf][nf] =          \
        __builtin_amdgcn_mfma_f32_16x16x32_f16(afv[1][mf], bh,               \
                                               accs[mf][nf], 0, 0, 0);       \
    _Pragma("unroll") for (int mf = 0; mf < 4; ++mf) accs[mf][nf] =          \
        __builtin_amdgcn_mfma_f32_16x16x32_f16(afv[1][mf], blv,              \
                                               accs[mf][nf], 0, 0, 0);       \
  }

// ---------------------------------------------------------------------------
// MFMA GEMM (NN): out = act(A[M,1024]_fp32 * Bsp + bias). Bsp pre-split fp16
// [n][k], limb planes at stride bplane. Tile 128x128, BK=32, 256 threads,
// wave-tile 64x64 (4x4 frags of mfma_f32_16x16x32_f16). LDS 32KB:
// Ah@0, Al@8192, Bh@16384, Bl@24576; 16B-chunk XOR swizzle
// phi(r)=((r>>1)^(r>>3))&3 (proven conflict-clean, rounds 5-7).
// If n0 >= 1024 the block writes C1/bias1 at col-1024 (fused dual output).
// ---------------------------------------------------------------------------
template <bool LEAKY>
__global__ __launch_bounds__(256, 3) void gemm_mfma_kernel(
    const float* __restrict__ A, const unsigned short* __restrict__ Bsp,
    long long bplane, float* __restrict__ C0, float* __restrict__ C1,
    const float* __restrict__ bias0, const float* __restrict__ bias1) {
  const int m0 = blockIdx.y * 128;
  const int n0 = blockIdx.x * 128;
  __shared__ __align__(16) char lds[32768];
  const int t = threadIdx.x;
  const int L = t & 63, w = t >> 6, q = L >> 4, l15 = L & 15;

  const int ar = t >> 1, ah = t & 1;
  const float* aptr = A + (long long)(m0 + ar) * 1024 + ah * 16;
  const int phiA = ((ar >> 1) ^ (ar >> 3)) & 3;
  const int wa0 = ar * 64 + (((2 * ah + 0) ^ phiA) << 4);
  const int wa1 = ar * 64 + (((2 * ah + 1) ^ phiA) << 4);

  int offA0[4], offB0[4];
#pragma unroll
  for (int f = 0; f < 4; ++f) {
    int rowa = ((w & 1) << 6) + (f << 4) + l15;
    offA0[f] = rowa * 64 + ((q ^ (((rowa >> 1) ^ (rowa >> 3)) & 3)) << 4);
    int rowb = ((w >> 1) << 6) + (f << 4) + l15;
    offB0[f] =
        16384 + rowb * 64 + ((q ^ (((rowb >> 1) ^ (rowb >> 3)) & 3)) << 4);
  }

  f32x4 acc[4][4];
#pragma unroll
  for (int i = 0; i < 4; ++i)
#pragma unroll
    for (int j = 0; j < 4; ++j) acc[i][j] = (f32x4){0.f, 0.f, 0.f, 0.f};

  for (int k0 = 0; k0 < 1024; k0 += 32) {
    // B staging: 4 x 16B per thread (pre-split fp16, swizzled dest)
#pragma unroll
    for (int j = 0; j < 4; ++j) {
      int fc = t + (j << 8);  // 0..1023
      int s = fc >> 9, r = (fc >> 2) & 127, sc = fc & 3;
      const unsigned short* bs = Bsp + s * bplane;
      uint4 bv =
          *(const uint4*)(bs + (long long)(n0 + r) * 1024 + k0 + (sc << 3));
      int phi = ((r >> 1) ^ (r >> 3)) & 3;
      *(uint4*)&lds[16384 + s * 8192 + r * 64 + ((sc ^ phi) << 4)] = bv;
    }
    // A staging: 16 fp32 -> 2 x 16 fp16 limbs
    {
      float4 a0 = *(const float4*)(aptr + k0);
      float4 a1 = *(const float4*)(aptr + k0 + 4);
      float4 a2 = *(const float4*)(aptr + k0 + 8);
      float4 a3 = *(const float4*)(aptr + k0 + 12);
      float xs[16] = {a0.x, a0.y, a0.z, a0.w, a1.x, a1.y, a1.z, a1.w,
                      a2.x, a2.y, a2.z, a2.w, a3.x, a3.y, a3.z, a3.w};
      split_store16f(xs, lds, 0, wa0, wa1);
    }
    __syncthreads();
    f16x8 af[2][4];
#pragma unroll
    for (int s = 0; s < 2; ++s)
#pragma unroll
      for (int f = 0; f < 4; ++f)
        af[s][f] = *(const f16x8*)&lds[s * 8192 + offA0[f]];
#pragma unroll
    for (int nf = 0; nf < 4; ++nf) {
      f16x8 bh = *(const f16x8*)&lds[offB0[nf]];
      f16x8 bl = *(const f16x8*)&lds[8192 + offB0[nf]];
      MFMA4(af, bh, bl, acc, nf);
    }
    __syncthreads();
  }

  const bool isR = (n0 >= 1024);
  float* Co = isR ? C1 : C0;
  const float* bp = isR ? bias1 : bias0;
  const int nc0 = n0 & 1023;
#pragma unroll
  for (int nf = 0; nf < 4; ++nf) {
    int col = nc0 + ((w >> 1) << 6) + (nf << 4) + l15;
    float bz = bp[col];
#pragma unroll
    for (int mf = 0; mf < 4; ++mf) {
#pragma unroll
      for (int r = 0; r < 4; ++r) {
        int row = m0 + ((w & 1) << 6) + (mf << 4) + (q << 2) + r;
        float x = acc[mf][nf][r] + bz;
        if (LEAKY) x = (x > 0.f) ? x : 0.1f * x;
        Co[(long long)row * 1024 + col] = x;
      }
    }
  }
}

// ---------------------------------------------------------------------------
// Batched NT GEMM on MFMA: C[b] = tmpA[b] * rights[b]^T + rowAdd + scal.
// Both operands fp32, split in-kernel to fp16x2. Tile 128x128, grid (2,2,64).
// ---------------------------------------------------------------------------
__global__ __launch_bounds__(256, 3) void gemmnt_mfma_kernel(
    const float* __restrict__ A, const float* __restrict__ B,
    float* __restrict__ C, const float* __restrict__ rowAdd,
    const float* __restrict__ scal) {
  const int bz = blockIdx.z;
  A += (long long)bz * 256 * 1024;
  B += (long long)bz * 256 * 1024;
  C += (long long)bz * 256 * 256;
  const int m0 = blockIdx.y * 128;
  const int n0 = blockIdx.x * 128;
  __shared__ __align__(16) char lds[32768];
  const int t = threadIdx.x;
  const int L = t & 63, w = t >> 6, q = L >> 4, l15 = L & 15;

  const int ar = t >> 1, ah = t & 1;
  const float* aptr = A + (long long)(m0 + ar) * 1024 + ah * 16;
  const float* bptr = B + (long long)(n0 + ar) * 1024 + ah * 16;
  const int phiA = ((ar >> 1) ^ (ar >> 3)) & 3;
  const int wa0 = ar * 64 + (((2 * ah + 0) ^ phiA) << 4);
  const int wa1 = ar * 64 + (((2 * ah + 1) ^ phiA) << 4);

  int offA0[4], offB0[4];
#pragma unroll
  for (int f = 0; f < 4; ++f) {
    int rowa = ((w & 1) << 6) + (f << 4) + l15;
    offA0[f] = rowa * 64 + ((q ^ (((rowa >> 1) ^ (rowa >> 3)) & 3)) << 4);
    int rowb = ((w >> 1) << 6) + (f << 4) + l15;
    offB0[f] =
        16384 + rowb * 64 + ((q ^ (((rowb >> 1) ^ (rowb >> 3)) & 3)) << 4);
  }

  f32x4 acc[4][4];
#pragma unroll
  for (int i = 0; i < 4; ++i)
#pragma unroll
    for (int j = 0; j < 4; ++j) acc[i][j] = (f32x4){0.f, 0.f, 0.f, 0.f};

  for (int k0 = 0; k0 < 1024; k0 += 32) {
    {
      float4 a0 = *(const float4*)(aptr + k0);
      float4 a1 = *(const float4*)(aptr + k0 + 4);
      float4 a2 = *(const float4*)(aptr + k0 + 8);
      float4 a3 = *(const float4*)(aptr + k0 + 12);
      float xs[16] = {a0.x, a0.y, a0.z, a0.w, a1.x, a1.y, a1.z, a1.w,
                      a2.x, a2.y, a2.z, a2.w, a3.x, a3.y, a3.z, a3.w};
      split_store16f(xs, lds, 0, wa0, wa1);
      float4 b0 = *(const float4*)(bptr + k0);
      float4 b1 = *(const float4*)(bptr + k0 + 4);
      float4 b2 = *(const float4*)(bptr + k0 + 8);
      float4 b3 = *(const float4*)(bptr + k0 + 12);
      float ys[16] = {b0.x, b0.y, b0.z, b0.w, b1.x, b1.y, b1.z, b1.w,
                      b2.x, b2.y, b2.z, b2.w, b3.x, b3.y, b3.z, b3.w};
      split_store16f(ys, lds, 16384, wa0, wa1);
    }
    __syncthreads();
    f16x8 af[2][4];
#pragma unroll
    for (int s = 0; s < 2; ++s)
#pragma unroll
      for (int f = 0; f < 4; ++f)
        af[s][f] = *(const f16x8*)&lds[s * 8192 + offA0[f]];
#pragma unroll
    for (int nf = 0; nf < 4; ++nf) {
      f16x8 bh = *(const f16x8*)&lds[offB0[nf]];
      f16x8 bl = *(const f16x8*)&lds[8192 + offB0[nf]];
      MFMA4(af, bh, bl, acc, nf);
    }
    __syncthreads();
  }

  const float sc_add = scal[0];
#pragma unroll
  for (int mf = 0; mf < 4; ++mf) {
#pragma unroll
    for (int r = 0; r < 4; ++r) {
      int row = m0 + ((w & 1) << 6) + (mf << 4) + (q << 2) + r;
      float radd = sc_add + rowAdd[(long long)bz * 256 + row];
#pragma unroll
      for (int nf = 0; nf < 4; ++nf) {
        int col = n0 + ((w >> 1) << 6) + (nf << 4) + l15;
        C[(long long)row * 256 + col] = acc[mf][nf][r] + radd;
      }
    }
  }
}

// ---------------------------------------------------------------------------
// tmpb[i] = dot(lefts[i,:], Wbil[0:H, H]) + Wbil[H,H].  One wave per row.
// ---------------------------------------------------------------------------
__global__ __launch_bounds__(64) void colvec_kernel(
    const float* __restrict__ lefts, const float* __restrict__ bcol,
    const float* __restrict__ corner, float* __restrict__ tmpb) {
  int row = blockIdx.x;
  int lane = threadIdx.x;
  const float* a = lefts + (long long)row * Hh;
  float s = 0.f;
#pragma unroll
  for (int h = lane; h < Hh; h += 64) s = fmaf(a[h], bcol[h], s);
#pragma unroll
  for (int off = 32; off > 0; off >>= 1) s += __shfl_down(s, off, 64);
  if (lane == 0) tmpb[row] = s + corner[0];
}

// ---------------------------------------------------------------------------
// CKY + backtrack. One block per batch, 1024 threads. Chart in LDS, packed
// triangular diag-major. TWO diagonals per barrier (see header comment).
// Partial slot layout: pv[pb][(sg<<lgS)+u], groups [0,Gh) = even diag,
// [Gh,2Gh) = odd diag; written by (b) with the CONSUMING superstep's params.
// ---------------------------------------------------------------------------
__global__ __launch_bounds__(1024) void cky_kernel(
    const float* __restrict__ scores,  // [64][256][256]
    uint8_t* __restrict__ Sws,         // [64][32896] packed triangular
    int* __restrict__ out)             // [2][64][256] int32
{
  const int b = blockIdx.x;
  const int t = threadIdx.x;
  const int n = Ss;
  const float* sc = scores + (long long)b * n * n;
  uint8_t* SP = Sws + (long long)b * 32896;

  __shared__ float Dch[32896];
  __shared__ float pv[2][2048];
  __shared__ uint8_t pmv[2][2048];
  __shared__ int stk[256];

  const int off1c = 256;   // off(1)
  const int off2c = 511;   // off(2)

  // prologue: diag0 = 0, diag1 = scores (split m=0), pv[0] = -inf
  if (t < n) {
    out[b * n + t] = 0;
    out[Bb * n + b * n + t] = 0;
    Dch[t] = 0.f;
  }
  if (t < n - 1) {
    Dch[off1c + t] = sc[t * 257 + 1];
    SP[off1c + t] = 0;
  }
  pv[0][t] = -3.0e38f;
  pv[0][t + 1024] = -3.0e38f;

  // prefetch scores for superstep 1 (diags 2, 3)
  float scA1 = 0.f, scA2 = 0.f, scA1b = 0.f;
  if (t < 254) scA1 = sc[t * 257 + 2];
  if (t < 253) scA2 = sc[t * 257 + 3];
  if ((t & 63) == 63 && t + 1 < 254) scA1b = sc[(t + 1) * 257 + 2];

  asm volatile("s_waitcnt lgkmcnt(0)\n\ts_barrier" ::: "memory");

  for (int s = 1; s <= 127; ++s) {
    const int w1 = 2 * s, w2 = w1 + 1;
    const int nv1 = n - w1, nv2 = nv1 - 1;
    const int pb = s & 1, po = pb ^ 1;
    // (a)-side params (== what (b) of superstep s-1 used)
    int lgSa, Gha;
    if (nv1 > 128) { lgSa = 8; Gha = 4; } else { lgSa = 7; Gha = 8; }
    const float* pvo = pv[po];
    const uint8_t* pmo = pmv[po];

    // prefetch next superstep's scores (diags w1+2, w2+2)
    float P1 = 0.f, P2 = 0.f, P1b = 0.f;
    if (s < 127) {
      if (t < nv1 - 2) P1 = sc[t * 257 + w1 + 2];
      if (t < nv1 - 3) P2 = sc[t * 257 + w1 + 3];
      if ((t & 63) == 63 && t + 1 < nv1 - 2) P1b = sc[(t + 1) * 257 + w1 + 2];
    }

    const int offW1 = w1 * n - ((w1 * (w1 - 1)) >> 1);
    const int offW1m1 = offW1 - (nv1 + 1);  // off(w1-1)
    const int offW1m2 = offW1m1 - (nv1 + 2);
    const int offW2 = offW1 + nv1;
    const int offW2m2 = offW1m1;  // w2-2 == w1-1
    const int offW2m3 = offW1m2;  // w2-3 == w1-2

    // exact reduce for diag w1 at a cell (shared by primary + lane-63 dup)
    auto reduceW1 = [&](int cell, float scv, int& bmOut) -> float {
      float bb = Dch[offW1m1 + cell + 1];  // m=0: 0 + right
      int bm = 0;
      float c1 = Dch[off1c + cell] + Dch[offW1m2 + cell + 2];
      if (c1 > bb) { bb = c1; bm = 1; }
#pragma unroll 4
      for (int g2 = 0; g2 < Gha; ++g2) {
        int sl = (g2 << lgSa) + cell;
        float x = pvo[sl];
        if (x > bb) { bb = x; bm = pmo[sl]; }
      }
      float cA = Dch[offW1m2 + cell] + Dch[off1c + cell + w1 - 1];
      if (cA > bb) { bb = cA; bm = w1 - 2; }
      float cB = Dch[offW1m1 + cell];  // m=w1-1: left + 0
      if (cB > bb) { bb = cB; bm = w1 - 1; }
      bmOut = bm;
      return scv + bb;
    };

    // ---- (a): finalize diags w1, w2 (wave-uniform gate) ----
    if ((t & ~63) < nv1) {
      const int tc = (t < nv1) ? t : (nv1 - 1);
      int bm1;
      float VAL1 = reduceW1(tc, scA1, bm1);
      if (t < nv1) {
        Dch[offW1 + t] = VAL1;
        SP[offW1 + t] = (uint8_t)bm1;
      }
      float v1n = __shfl_down(VAL1, 1, 64);
      if ((t & 63) == 63 && t < nv2) {
        int dummy;
        v1n = reduceW1(t + 1, scA1b, dummy);  // bit-identical to lane t+1
      }
      if (t < nv2) {
        float bb2 = v1n;  // m=0: 0 + VAL_w1(t+1)
        int bm2 = 0;
        float d1 = Dch[off1c + t] + Dch[offW2m2 + t + 2];
        if (d1 > bb2) { bb2 = d1; bm2 = 1; }
        float d2 = Dch[off2c + t] + Dch[offW2m3 + t + 3];
        if (d2 > bb2) { bb2 = d2; bm2 = 2; }
#pragma unroll 4
        for (int g2 = Gha; g2 < 2 * Gha; ++g2) {
          int sl = (g2 << lgSa) + t;
          float x = pvo[sl];
          if (x > bb2) { bb2 = x; bm2 = pmo[sl]; }
        }
        if (w2 > 3) {  // at s=1 this duplicates m=0 and would race on diag2
          float dA = Dch[offW2m3 + t] + Dch[off2c + t + w2 - 2];
          if (dA > bb2) { bb2 = dA; bm2 = w2 - 3; }
        }
        float dB = Dch[offW2m2 + t] + Dch[off1c + t + w2 - 1];
        if (dB > bb2) { bb2 = dB; bm2 = w2 - 2; }
        if (VAL1 > bb2) { bb2 = VAL1; bm2 = w2 - 1; }  // m=w2-1: left + 0
        Dch[offW2 + t] = scA2 + bb2;
        SP[offW2 + t] = (uint8_t)bm2;
      }
    }

    // ---- (b): middle partials for diags w1+2 (half 0), w2+2 (half 1) ----
    if (s < 127) {
      const int nv1n = nv1 - 2;  // cells of diag w1+2 (next superstep)
      int lgT2, d2v, lgS2, Gh2, lgGh2;
      if (nv1n > 128) {
        lgT2 = 7; d2v = 128; lgS2 = 8; Gh2 = 4; lgGh2 = 2;
      } else if (nv1n > 64) {
        lgT2 = 6; d2v = 64; lgS2 = 7; Gh2 = 8; lgGh2 = 3;
      } else {
        lgT2 = 6; d2v = 0; lgS2 = 7; Gh2 = 8; lgGh2 = 3;
      }
      const int gg = t >> lgT2;
      const int u = t & ((1 << lgT2) - 1);
      const int half = gg >> lgGh2;          // 0: w1+2, 1: w2+2
      const int graw = gg & (Gh2 - 1);
      const int g = Gh2 - 1 - graw;          // reversed: low waves get tails
      const int W = w1 + 2 + half;
      const int mlo = 2 + half;
      const int bnd = W - 2 - half;          // exclusive upper bound on m
      const int cnt = bnd - mlo;
      const int per = (cnt + Gh2 - 1) >> lgGh2;
      int ml = mlo + g * per;
      int mh = ml + per;
      if (mh > bnd) mh = bnd;
      const int nvW = n - W;
      float b0 = -3.0e38f, b1 = -3.0e38f;
      int m0i = mlo, m1i = mlo;
      if (u < nvW && ml < mh) {
        int al = ml * n - ((ml * (ml - 1)) >> 1) + u;
        const int kr = W - 1 - ml;
        int ar = kr * n - ((kr * (kr - 1)) >> 1) + u + ml + 1;
        int dl = n - ml;
        int dr = n - W + ml + 1;
        if (d2v) {
#pragma unroll 2
          for (int m = ml; m < mh; ++m) {
            float l0 = Dch[al], l1 = Dch[al + d2v];  // -> ds_read2_b32
            float r0 = Dch[ar], r1 = Dch[ar + d2v];  // -> ds_read2_b32
            float c0 = l0 + r0, c1 = l1 + r1;
            if (c0 > b0) { b0 = c0; m0i = m; }  // strict > = first max
            if (c1 > b1) { b1 = c1; m1i = m; }
            al += dl;
            ar -= dr;
            --dl;
            ++dr;
          }
        } else {
#pragma unroll 4
          for (int m = ml; m < mh; ++m) {
            float c = Dch[al] + Dch[ar];
            if (c > b0) { b0 = c; m0i = m; }
            al += dl;
            ar -= dr;
            --dl;
            ++dr;
          }
        }
      }
      const int sg = (half << lgGh2) + g;
      const int sl = (sg << lgS2) + u;
      pv[pb][sl] = b0;
      pmv[pb][sl] = (uint8_t)m0i;
      if (d2v) {
        pv[pb][sl + d2v] = b1;
        pmv[pb][sl + d2v] = (uint8_t)m1i;
      }
    }

    // LDS-ordering barrier only; SP global stores stay in flight.
    asm volatile("s_waitcnt lgkmcnt(0)\n\ts_barrier" ::: "memory");
    scA1 = P1;
    scA2 = P2;
    scA1b = P1b;
  }

  // Drain all SP stores (whole loop's worth) once, then barrier.
  asm volatile("s_waitcnt vmcnt(0) lgkmcnt(0)\n\ts_barrier" ::: "memory");
  uint8_t* spl = (uint8_t*)Dch;
  for (int idx = t; idx < 32896; idx += 1024) spl[idx] = SP[idx];
  asm volatile("s_waitcnt vmcnt(0) lgkmcnt(0)\n\ts_barrier" ::: "memory");
  if (t == 0) {
    int top = 0;
    stk[top++] = (0 << 16) | (n - 1);
    int cnt = 0;
    for (int step = 0; step < n - 1; ++step) {
      if (top > 0) {
        int ij = stk[--top];
        int ii = ij >> 16, jj = ij & 0xffff;
        out[b * n + cnt] = ii;
        out[Bb * n + b * n + cnt] = jj;
        ++cnt;
        int k = jj - ii;
        int s2 = ii + (int)spl[k * n - ((k * (k - 1)) >> 1) + ii];
        stk[top] = (ii << 16) | s2;
        if (s2 > ii) ++top;
        stk[top] = ((s2 + 1) << 16) | jj;
        if (jj > s2 + 1) ++top;
      }
    }
  }
}

// ---------------------------------------------------------------------------
// Launch
// ---------------------------------------------------------------------------
extern "C" void kernel_launch(void* const* d_in, const int* in_sizes, int n_in,
                              void* d_out, int out_size, void* d_ws,
                              size_t ws_size, hipStream_t stream) {
  const float* X = (const float*)d_in[0];     // [64,256,1024]
  const float* Wl = (const float*)d_in[2];    // [1024,1024]
  const float* bl = (const float*)d_in[3];    // [1024]
  const float* Wr = (const float*)d_in[4];
  const float* br = (const float*)d_in[5];
  const float* Wbil = (const float*)d_in[6];  // [1025,1025]
  const float* bbil = (const float*)d_in[7];  // scalar
  int* out = (int*)d_out;

  // workspace layout
  float* ws = (float*)d_ws;
  float* lefts = ws;                          // 16777216 f
  float* rights = lefts + 16777216;           // 16777216 f
  float* tmpA = rights + 16777216;            // 16777216 f
  float* scoresP = tmpA + 16777216;           // 4194304 f
  float* tmpb = scoresP + 4194304;            // 16384 f
  float* browp = tmpb + 16384;                // 1024 f
  float* bcolp = browp + 1024;                // 1024 f
  float* cornerp = bcolp + 1024;              // 4 f
  unsigned short* Wlrt = (unsigned short*)(cornerp + 4);  // 2 x 2M fp16
  unsigned short* Wct = Wlrt + 2LL * 2097152;             // 2 x 1M fp16
  uint8_t* SPp = (uint8_t*)(Wct + 2LL * 1048576);         // 64x32896 u8

  // weight splits (+ Wbil bias vectors)
  splitw_kernel<<<dim3(4096), 256, 0, stream>>>(Wl, 1024, Wlrt, 2097152);
  splitw_kernel<<<dim3(4096), 256, 0, stream>>>(Wr, 1024, Wlrt + 1048576,
                                                2097152);
  splitw_kernel<<<dim3(4096), 256, 0, stream>>>(Wbil, 1025, Wct, 1048576);
  bilvec_kernel<<<dim3(4), 256, 0, stream>>>(Wbil, browp, bcolp, cornerp);

  // fused lefts|rights GEMM: N=2048
  dim3 gLR(16, 128);
  gemm_mfma_kernel<true><<<gLR, 256, 0, stream>>>(X, Wlrt, 2097152LL, lefts,
                                                  rights, bl, br);

  colvec_kernel<<<dim3(16384), 64, 0, stream>>>(lefts, bcolp, cornerp, tmpb);

  dim3 gA(8, 128);
  gemm_mfma_kernel<false><<<gA, 256, 0, stream>>>(lefts, Wct, 1048576LL, tmpA,
                                                  tmpA, browp, browp);

  dim3 g3(2, 2, 64);
  gemmnt_mfma_kernel<<<g3, 256, 0, stream>>>(tmpA, rights, scoresP, tmpb,
                                             bbil);

  cky_kernel<<<dim3(Bb), dim3(1024), 0, stream>>>(scoresP, SPp, out);
}

// Round 3
// 943.726 us; speedup vs baseline: 1.3019x; 1.0907x over previous
//
#include <hip/hip_runtime.h>
#include <cstdint>

// ---------------------------------------------------------------------------
// ChartParser: span scores + per-batch CKY DP + backtrack.
// B=64, S=256, D=H=1024. Output: int32 [2][B][S] (lefts then rights).
// Round 11: CKY processes FOUR diagonals per barrier.
//  Superstep s (s=3..64) finalizes diags W0..W0+3 (W0=4s-2) in phase (a)
//  using partials from phase (b) of s-1, which covered m in [j+4, W0-5]
//  (exactly the spans >= 1 barrier old). The 2j+8 extreme candidates are
//  evaluated in (a): current-batch left spans from own registers, right
//  spans via __shfl_down (distance <= 3). (a)-waves use bands of stride 61
//  (3-lane overlap; boundary cells recomputed bit-identically by the next
//  band). Prologue computes diags 1..9 generically (one barrier each) plus
//  the first (b) pass, eliminating all small-W special cases.
//  Candidate order is strictly ascending in m everywhere with strict '>':
//  dyn-low [0,j-1] | static-low [j,j+3] | partials [j+4,W0-5] |
//  static-high [W0-4,W0-1] | dyn-high [W0,W-1]  — contiguous, exact
//  jnp.argmax first-max semantics. pv stays 2048 slots (regime-dependent
//  group layout), LDS unchanged at 153088 B.
// ---------------------------------------------------------------------------

#define Bb 64
#define Ss 256
#define Dd 1024
#define Hh 1024

typedef __attribute__((ext_vector_type(8))) _Float16 f16x8;
typedef __attribute__((ext_vector_type(4))) float f32x4;

// x = h + l + delta, |delta| <= 2^-22 |x| (fp16 RNE twice)
__device__ __forceinline__ void split2(float x, unsigned short& h,
                                       unsigned short& l) {
  _Float16 hh = (_Float16)x;
  _Float16 ll = (_Float16)(x - (float)hh);
  h = __builtin_bit_cast(unsigned short, hh);
  l = __builtin_bit_cast(unsigned short, ll);
}

// ---------------------------------------------------------------------------
// Weight split+transpose: W fp32 [1024 k-rows, ld ldw] -> O fp16 [n][k],
// limb planes at +0, +plane.
// ---------------------------------------------------------------------------
__global__ __launch_bounds__(256) void splitw_kernel(
    const float* __restrict__ W, int ldw, unsigned short* __restrict__ O,
    long long plane) {
  int idx = blockIdx.x * 256 + threadIdx.x;  // n*1024 + k
  int n = idx >> 10, k = idx & 1023;
  float x = W[(long long)k * ldw + n];
  unsigned short h, l;
  split2(x, h, l);
  O[idx] = h;
  O[plane + idx] = l;
}

// Extract Wbil's bias row / col / corner.
__global__ __launch_bounds__(256) void bilvec_kernel(
    const float* __restrict__ Wbil, float* __restrict__ brow,
    float* __restrict__ bcol, float* __restrict__ corner) {
  int i = blockIdx.x * 256 + threadIdx.x;  // 0..1023
  brow[i] = Wbil[1024 * 1025 + i];
  bcol[i] = Wbil[i * 1025 + 1024];
  if (i == 0) corner[0] = Wbil[1024 * 1025 + 1024];
}

__device__ __forceinline__ void pack8(char* dst, const unsigned short* v) {
  uint4 u;
  u.x = (unsigned)v[0] | ((unsigned)v[1] << 16);
  u.y = (unsigned)v[2] | ((unsigned)v[3] << 16);
  u.z = (unsigned)v[4] | ((unsigned)v[5] << 16);
  u.w = (unsigned)v[6] | ((unsigned)v[7] << 16);
  *(uint4*)dst = u;
}

// split 16 fp32 -> 2x16 fp16 limbs, store (swizzled) to 2 LDS planes
__device__ __forceinline__ void split_store16f(const float* xs, char* lds,
                                               int base, int wa0, int wa1) {
  unsigned short hs[16], ls[16];
#pragma unroll
  for (int i = 0; i < 16; ++i) split2(xs[i], hs[i], ls[i]);
  pack8(&lds[base + wa0], hs);
  pack8(&lds[base + wa1], hs + 8);
  pack8(&lds[base + 8192 + wa0], ls);
  pack8(&lds[base + 8192 + wa1], ls + 8);
}

// 4-product accumulate for one nf column: (ah+al)x(bh+bl), all kept
#define MFMA4(afv, bh, blv, accs, nf)                                        \
  {                                                                          \
    _Pragma("unroll") for (int mf = 0; mf < 4; ++mf) accs[mf][nf] =          \
        __builtin_amdgcn_mfma_f32_16x16x32_f16(afv[0][mf], bh,               \
                                               accs[mf][nf], 0, 0, 0);       \
    _Pragma("unroll") for (int mf = 0; mf < 4; ++mf) accs[mf][nf] =          \
        __builtin_amdgcn_mfma_f32_16x16x32_f16(afv[0][mf], blv,              \
                                               accs[mf][nf], 0, 0, 0);       \
    _Pragma("unroll") for (int mf = 0; mf < 4; ++mf) accs[mf][nf] =          \
        __builtin_amdgcn_mfma_f32_16x16x32_f16(afv[1][mf], bh,               \
                                               accs[mf][nf], 0, 0, 0);       \
    _Pragma("unroll") for (int mf = 0; mf < 4; ++mf) accs[mf][nf] =          \
        __builtin_amdgcn_mfma_f32_16x16x32_f16(afv[1][mf], blv,              \
                                               accs[mf][nf], 0, 0, 0);       \
  }

// ---------------------------------------------------------------------------
// MFMA GEMM (NN): out = act(A[M,1024]_fp32 * Bsp + bias). Bsp pre-split fp16
// [n][k], limb planes at stride bplane. Tile 128x128, BK=32, 256 threads,
// wave-tile 64x64 (4x4 frags of mfma_f32_16x16x32_f16). LDS 32KB:
// Ah@0, Al@8192, Bh@16384, Bl@24576; 16B-chunk XOR swizzle
// phi(r)=((r>>1)^(r>>3))&3 (proven conflict-clean, rounds 5-7).
// If n0 >= 1024 the block writes C1/bias1 at col-1024 (fused dual output).
// ---------------------------------------------------------------------------
template <bool LEAKY>
__global__ __launch_bounds__(256, 3) void gemm_mfma_kernel(
    const float* __restrict__ A, const unsigned short* __restrict__ Bsp,
    long long bplane, float* __restrict__ C0, float* __restrict__ C1,
    const float* __restrict__ bias0, const float* __restrict__ bias1) {
  const int m0 = blockIdx.y * 128;
  const int n0 = blockIdx.x * 128;
  __shared__ __align__(16) char lds[32768];
  const int t = threadIdx.x;
  const int L = t & 63, w = t >> 6, q = L >> 4, l15 = L & 15;

  const int ar = t >> 1, ah = t & 1;
  const float* aptr = A + (long long)(m0 + ar) * 1024 + ah * 16;
  const int phiA = ((ar >> 1) ^ (ar >> 3)) & 3;
  const int wa0 = ar * 64 + (((2 * ah + 0) ^ phiA) << 4);
  const int wa1 = ar * 64 + (((2 * ah + 1) ^ phiA) << 4);

  int offA0[4], offB0[4];
#pragma unroll
  for (int f = 0; f < 4; ++f) {
    int rowa = ((w & 1) << 6) + (f << 4) + l15;
    offA0[f] = rowa * 64 + ((q ^ (((rowa >> 1) ^ (rowa >> 3)) & 3)) << 4);
    int rowb = ((w >> 1) << 6) + (f << 4) + l15;
    offB0[f] =
        16384 + rowb * 64 + ((q ^ (((rowb >> 1) ^ (rowb >> 3)) & 3)) << 4);
  }

  f32x4 acc[4][4];
#pragma unroll
  for (int i = 0; i < 4; ++i)
#pragma unroll
    for (int j = 0; j < 4; ++j) acc[i][j] = (f32x4){0.f, 0.f, 0.f, 0.f};

  for (int k0 = 0; k0 < 1024; k0 += 32) {
    // B staging: 4 x 16B per thread (pre-split fp16, swizzled dest)
#pragma unroll
    for (int j = 0; j < 4; ++j) {
      int fc = t + (j << 8);  // 0..1023
      int s = fc >> 9, r = (fc >> 2) & 127, sc = fc & 3;
      const unsigned short* bs = Bsp + s * bplane;
      uint4 bv =
          *(const uint4*)(bs + (long long)(n0 + r) * 1024 + k0 + (sc << 3));
      int phi = ((r >> 1) ^ (r >> 3)) & 3;
      *(uint4*)&lds[16384 + s * 8192 + r * 64 + ((sc ^ phi) << 4)] = bv;
    }
    // A staging: 16 fp32 -> 2 x 16 fp16 limbs
    {
      float4 a0 = *(const float4*)(aptr + k0);
      float4 a1 = *(const float4*)(aptr + k0 + 4);
      float4 a2 = *(const float4*)(aptr + k0 + 8);
      float4 a3 = *(const float4*)(aptr + k0 + 12);
      float xs[16] = {a0.x, a0.y, a0.z, a0.w, a1.x, a1.y, a1.z, a1.w,
                      a2.x, a2.y, a2.z, a2.w, a3.x, a3.y, a3.z, a3.w};
      split_store16f(xs, lds, 0, wa0, wa1);
    }
    __syncthreads();
    f16x8 af[2][4];
#pragma unroll
    for (int s = 0; s < 2; ++s)
#pragma unroll
      for (int f = 0; f < 4; ++f)
        af[s][f] = *(const f16x8*)&lds[s * 8192 + offA0[f]];
#pragma unroll
    for (int nf = 0; nf < 4; ++nf) {
      f16x8 bh = *(const f16x8*)&lds[offB0[nf]];
      f16x8 bl = *(const f16x8*)&lds[8192 + offB0[nf]];
      MFMA4(af, bh, bl, acc, nf);
    }
    __syncthreads();
  }

  const bool isR = (n0 >= 1024);
  float* Co = isR ? C1 : C0;
  const float* bp = isR ? bias1 : bias0;
  const int nc0 = n0 & 1023;
#pragma unroll
  for (int nf = 0; nf < 4; ++nf) {
    int col = nc0 + ((w >> 1) << 6) + (nf << 4) + l15;
    float bz = bp[col];
#pragma unroll
    for (int mf = 0; mf < 4; ++mf) {
#pragma unroll
      for (int r = 0; r < 4; ++r) {
        int row = m0 + ((w & 1) << 6) + (mf << 4) + (q << 2) + r;
        float x = acc[mf][nf][r] + bz;
        if (LEAKY) x = (x > 0.f) ? x : 0.1f * x;
        Co[(long long)row * 1024 + col] = x;
      }
    }
  }
}

// ---------------------------------------------------------------------------
// Batched NT GEMM on MFMA: C[b] = tmpA[b] * rights[b]^T + rowAdd + scal.
// Both operands fp32, split in-kernel to fp16x2. Tile 128x128, grid (2,2,64).
// ---------------------------------------------------------------------------
__global__ __launch_bounds__(256, 3) void gemmnt_mfma_kernel(
    const float* __restrict__ A, const float* __restrict__ B,
    float* __restrict__ C, const float* __restrict__ rowAdd,
    const float* __restrict__ scal) {
  const int bz = blockIdx.z;
  A += (long long)bz * 256 * 1024;
  B += (long long)bz * 256 * 1024;
  C += (long long)bz * 256 * 256;
  const int m0 = blockIdx.y * 128;
  const int n0 = blockIdx.x * 128;
  __shared__ __align__(16) char lds[32768];
  const int t = threadIdx.x;
  const int L = t & 63, w = t >> 6, q = L >> 4, l15 = L & 15;

  const int ar = t >> 1, ah = t & 1;
  const float* aptr = A + (long long)(m0 + ar) * 1024 + ah * 16;
  const float* bptr = B + (long long)(n0 + ar) * 1024 + ah * 16;
  const int phiA = ((ar >> 1) ^ (ar >> 3)) & 3;
  const int wa0 = ar * 64 + (((2 * ah + 0) ^ phiA) << 4);
  const int wa1 = ar * 64 + (((2 * ah + 1) ^ phiA) << 4);

  int offA0[4], offB0[4];
#pragma unroll
  for (int f = 0; f < 4; ++f) {
    int rowa = ((w & 1) << 6) + (f << 4) + l15;
    offA0[f] = rowa * 64 + ((q ^ (((rowa >> 1) ^ (rowa >> 3)) & 3)) << 4);
    int rowb = ((w >> 1) << 6) + (f << 4) + l15;
    offB0[f] =
        16384 + rowb * 64 + ((q ^ (((rowb >> 1) ^ (rowb >> 3)) & 3)) << 4);
  }

  f32x4 acc[4][4];
#pragma unroll
  for (int i = 0; i < 4; ++i)
#pragma unroll
    for (int j = 0; j < 4; ++j) acc[i][j] = (f32x4){0.f, 0.f, 0.f, 0.f};

  for (int k0 = 0; k0 < 1024; k0 += 32) {
    {
      float4 a0 = *(const float4*)(aptr + k0);
      float4 a1 = *(const float4*)(aptr + k0 + 4);
      float4 a2 = *(const float4*)(aptr + k0 + 8);
      float4 a3 = *(const float4*)(aptr + k0 + 12);
      float xs[16] = {a0.x, a0.y, a0.z, a0.w, a1.x, a1.y, a1.z, a1.w,
                      a2.x, a2.y, a2.z, a2.w, a3.x, a3.y, a3.z, a3.w};
      split_store16f(xs, lds, 0, wa0, wa1);
      float4 b0 = *(const float4*)(bptr + k0);
      float4 b1 = *(const float4*)(bptr + k0 + 4);
      float4 b2 = *(const float4*)(bptr + k0 + 8);
      float4 b3 = *(const float4*)(bptr + k0 + 12);
      float ys[16] = {b0.x, b0.y, b0.z, b0.w, b1.x, b1.y, b1.z, b1.w,
                      b2.x, b2.y, b2.z, b2.w, b3.x, b3.y, b3.z, b3.w};
      split_store16f(ys, lds, 16384, wa0, wa1);
    }
    __syncthreads();
    f16x8 af[2][4];
#pragma unroll
    for (int s = 0; s < 2; ++s)
#pragma unroll
      for (int f = 0; f < 4; ++f)
        af[s][f] = *(const f16x8*)&lds[s * 8192 + offA0[f]];
#pragma unroll
    for (int nf = 0; nf < 4; ++nf) {
      f16x8 bh = *(const f16x8*)&lds[offB0[nf]];
      f16x8 bl = *(const f16x8*)&lds[8192 + offB0[nf]];
      MFMA4(af, bh, bl, acc, nf);
    }
    __syncthreads();
  }

  const float sc_add = scal[0];
#pragma unroll
  for (int mf = 0; mf < 4; ++mf) {
#pragma unroll
    for (int r = 0; r < 4; ++r) {
      int row = m0 + ((w & 1) << 6) + (mf << 4) + (q << 2) + r;
      float radd = sc_add + rowAdd[(long long)bz * 256 + row];
#pragma unroll
      for (int nf = 0; nf < 4; ++nf) {
        int col = n0 + ((w >> 1) << 6) + (nf << 4) + l15;
        C[(long long)row * 256 + col] = acc[mf][nf][r] + radd;
      }
    }
  }
}

// ---------------------------------------------------------------------------
// tmpb[i] = dot(lefts[i,:], Wbil[0:H, H]) + Wbil[H,H].  One wave per row.
// ---------------------------------------------------------------------------
__global__ __launch_bounds__(64) void colvec_kernel(
    const float* __restrict__ lefts, const float* __restrict__ bcol,
    const float* __restrict__ corner, float* __restrict__ tmpb) {
  int row = blockIdx.x;
  int lane = threadIdx.x;
  const float* a = lefts + (long long)row * Hh;
  float s = 0.f;
#pragma unroll
  for (int h = lane; h < Hh; h += 64) s = fmaf(a[h], bcol[h], s);
#pragma unroll
  for (int off = 32; off > 0; off >>= 1) s += __shfl_down(s, off, 64);
  if (lane == 0) tmpb[row] = s + corner[0];
}

// ---------------------------------------------------------------------------
// CKY + backtrack. One block per batch, 1024 threads. Chart in LDS, packed
// triangular diag-major. FOUR diagonals per barrier (see header comment).
// ---------------------------------------------------------------------------
__global__ __launch_bounds__(1024) void cky_kernel(
    const float* __restrict__ scores,  // [64][256][256]
    uint8_t* __restrict__ Sws,         // [64][32896] packed triangular
    int* __restrict__ out)             // [2][64][256] int32
{
  const int b = blockIdx.x;
  const int t = threadIdx.x;
  const int n = Ss;
  const float* sc = scores + (long long)b * n * n;
  uint8_t* SP = Sws + (long long)b * 32896;

  __shared__ float Dch[32896];
  __shared__ float pv[2][2048];
  __shared__ uint8_t pmv[2][2048];
  __shared__ int stk[256];

  // offsets of tiny diags 0..9 (compile-time constants)
  const int offT[10] = {0,    256,  511,  765,  1018,
                        1270, 1521, 1771, 2020, 2268};

  if (t < n) {
    out[b * n + t] = 0;
    out[Bb * n + b * n + t] = 0;
    Dch[t] = 0.f;  // diag 0
  }

  // prologue score prefetch (diags 1..9 at cell t, clamped addresses)
  float PS[10];
  PS[0] = 0.f;
#pragma unroll
  for (int w = 1; w <= 9; ++w) {
    int ic = t;
    if (ic > 255 - w) ic = 255 - w;
    PS[w] = sc[ic * 257 + w];
  }
  asm volatile("s_waitcnt lgkmcnt(0)\n\ts_barrier" ::: "memory");

  // prologue: diags 1..9, one barrier each (generic m-scan, ascending,
  // strict > = first-max)
#pragma unroll
  for (int w = 1; w <= 9; ++w) {
    const int nv = n - w;
    if (t < nv) {
      float bb = Dch[offT[w - 1] + t + 1];  // m=0: 0 + right
      int bm = 0;
#pragma unroll
      for (int m = 1; m < 9; ++m) {
        if (m >= w) break;
        float c = Dch[offT[m] + t] + Dch[offT[w - 1 - m] + t + m + 1];
        if (c > bb) { bb = c; bm = m; }
      }
      const int off = w * 256 - ((w * (w - 1)) >> 1);
      Dch[off + t] = PS[w] + bb;
      SP[off + t] = (uint8_t)bm;
    }
    asm volatile("s_waitcnt lgkmcnt(0)\n\ts_barrier" ::: "memory");
  }

  // generic (b): group partials for superstep with base W0b+4 (4 diags).
  // Covers m in [jb+4, W0b-1] (left/right spans are diags <= W0b-1, i.e.
  // >= 1 barrier old when run inside superstep W0b). Writes pv/pmv[pbuf].
  auto run_b = [&](int W0b, int pbuf) {
    const int cnv = n - W0b - 4;  // cells of consumer's first diag
    int jb, gb, u, delta, lgGHL, SLOTG;
    if (cnv > 128) {  // RA: 2 groups/diag, T=128, slices (u, u+128)
      const int p = t >> 7;
      jb = 3 - (p >> 1);
      gb = 1 - (p & 1);
      u = t & 127;
      delta = 128;
      lgGHL = 1;
      SLOTG = 256;
    } else {  // RB/RC: 4 groups/diag, T=64
      const int wid = t >> 6;
      jb = 3 - (wid >> 2);
      gb = 3 - (wid & 3);
      u = t & 63;
      delta = (cnv > 64) ? 64 : 0;
      lgGHL = 2;
      SLOTG = 128;
    }
    const int Wb = W0b + 4 + jb;
    const int nvb = n - Wb;
    int cnt = W0b - jb - 4;
    if (cnt < 0) cnt = 0;
    const int per = (cnt + (1 << lgGHL) - 1) >> lgGHL;
    const int mlo = jb + 4;
    int ml = mlo + gb * per;
    int mh = mlo + cnt;
    {
      int e = ml + per;
      if (e < mh) mh = e;
    }
    float b0 = -3.0e38f, b1 = -3.0e38f;
    int m0i = ml, m1i = ml;
    if (u < nvb && ml < mh) {
      int al = ml * n - ((ml * (ml - 1)) >> 1) + u;
      const int kr = Wb - 1 - ml;
      int ar = kr * n - ((kr * (kr - 1)) >> 1) + u + ml + 1;
      int dl = n - ml;
      int dr = n - Wb + ml + 1;
      if (delta) {
#pragma unroll 2
        for (int m = ml; m < mh; ++m) {
          float l0 = Dch[al], l1 = Dch[al + delta];  // -> ds_read2_b32
          float r0 = Dch[ar], r1 = Dch[ar + delta];  // -> ds_read2_b32
          float c0 = l0 + r0, c1 = l1 + r1;
          if (c0 > b0) { b0 = c0; m0i = m; }  // strict > = first max
          if (c1 > b1) { b1 = c1; m1i = m; }
          al += dl;
          ar -= dr;
          --dl;
          ++dr;
        }
      } else {
#pragma unroll 4
        for (int m = ml; m < mh; ++m) {
          float c = Dch[al] + Dch[ar];
          if (c > b0) { b0 = c; m0i = m; }
          al += dl;
          ar -= dr;
          --dl;
          ++dr;
        }
      }
    }
    const int slot = jb * 512 + gb * SLOTG + u;
    pv[pbuf][slot] = b0;
    pmv[pbuf][slot] = (uint8_t)m0i;
    if (delta) {
      pv[pbuf][slot + delta] = b1;
      pmv[pbuf][slot + delta] = (uint8_t)m1i;
    }
  };

  // prologue (b): partials for s=3 (diags 10..13), "s=2" role -> pv[0]
  run_b(6, 0);
  asm volatile("s_waitcnt lgkmcnt(0)\n\ts_barrier" ::: "memory");

  // (a)-band geometry: wave wv covers cells 61*wv + lane (3-lane overlap)
  const int wv = t >> 6, lane = t & 63;
  const int tcell = 61 * wv + lane;

  // seed scores for s=3 (diags 10..13)
  float scA[4];
#pragma unroll
  for (int j = 0; j < 4; ++j) {
    const int Wn = 10 + j;
    int ic = tcell;
    if (ic > 255 - Wn) ic = 255 - Wn;
    if (ic < 0) ic = 0;
    scA[j] = sc[ic * 257 + Wn];
  }

  for (int s = 3; s <= 64; ++s) {
    const int W0 = 4 * s - 2;
    const int nv1 = n - W0;
    const int pb = s & 1, po = pb ^ 1;
    const int nb = (nv1 + 60) / 61;

    // prefetch next superstep's scores (diags W0+4..W0+7)
    float P4[4] = {0.f, 0.f, 0.f, 0.f};
    if (s < 64 && wv < nb) {
#pragma unroll
      for (int j = 0; j < 4; ++j) {
        const int Wn = W0 + 4 + j;
        int ic = tcell;
        if (ic > 255 - Wn) ic = 255 - Wn;
        if (ic < 0) ic = 0;
        P4[j] = sc[ic * 257 + Wn];
      }
    }

    // ---- (a): finalize diags W0..W0+3 ----
    if (wv < nb) {
      const int tc = (tcell < nv1) ? tcell : (nv1 - 1);  // clamped (safe)
      const float* pvo = pv[po];
      const uint8_t* pmo = pmv[po];
      int GHa, SGa;
      if (nv1 > 128) { GHa = 2; SGa = 256; } else { GHa = 4; SGa = 128; }
      int offPB[4], offCB[4];
#pragma unroll
      for (int d = 0; d < 4; ++d) {
        const int dg = W0 - 4 + d;
        offPB[d] = dg * 256 - ((dg * (dg - 1)) >> 1);
        const int cg = W0 + d;
        offCB[d] = cg * 256 - ((cg * (cg - 1)) >> 1);
      }
      float VAL0, VAL1, VAL2, VAL3;
      float SH01, SH02, SH03, SH11, SH12, SH21;
      // ---------------- j = 0 (W = W0) ----------------
      {
        const int W = W0;
        float bb = Dch[offPB[3] + tc + 1];  // m=0: 0 + prev-batch diag W-1
        int bm = 0;
#pragma unroll
        for (int dm = 1; dm < 4; ++dm) {  // static-low m = dm
          const int m = dm;
          float c = Dch[offT[m] + tc] + Dch[offPB[3 - dm] + tc + m + 1];
          if (c > bb) { bb = c; bm = m; }
        }
#pragma unroll
        for (int g = 0; g < 4; ++g) {  // partials [4, W0-5]
          if (g >= GHa) break;
          const int sl = g * SGa + tc;
          float x = pvo[sl];
          if (x > bb) { bb = x; bm = pmo[sl]; }
        }
#pragma unroll
        for (int dr = 3; dr >= 0; --dr) {  // static-high m = W0-1-dr asc
          const int r = dr;
          const int m = W - 1 - r;
          float right = (r == 0) ? 0.f : Dch[offT[r] + tc + W - r];
          float c = Dch[offPB[3 - dr] + tc] + right;
          if (c > bb) { bb = c; bm = m; }
        }
        VAL0 = scA[0] + bb;
        if (tcell < nv1) {
          Dch[offCB[0] + tcell] = VAL0;
          SP[offCB[0] + tcell] = (uint8_t)bm;
        }
        SH01 = __shfl_down(VAL0, 1, 64);
        SH02 = __shfl_down(VAL0, 2, 64);
        SH03 = __shfl_down(VAL0, 3, 64);
      }
      // ---------------- j = 1 (W = W0+1) ----------------
      {
        const int W = W0 + 1;
        float bb = SH01;  // m=0: 0 + VAL0(t+1)
        int bm = 0;
#pragma unroll
        for (int dm = 0; dm < 4; ++dm) {  // static-low m = 1+dm
          const int m = 1 + dm;
          float c = Dch[offT[m] + tc] + Dch[offPB[3 - dm] + tc + m + 1];
          if (c > bb) { bb = c; bm = m; }
        }
#pragma unroll
        for (int g = 0; g < 4; ++g) {
          if (g >= GHa) break;
          const int sl = 512 + g * SGa + tc;
          float x = pvo[sl];
          if (x > bb) { bb = x; bm = pmo[sl]; }
        }
#pragma unroll
        for (int dr = 3; dr >= 0; --dr) {  // static-high r = 1+dr
          const int r = 1 + dr;
          const int m = W - 1 - r;  // = W0-1-dr, ascending
          float c = Dch[offPB[3 - dr] + tc] + Dch[offT[r] + tc + W - r];
          if (c > bb) { bb = c; bm = m; }
        }
        // dyn-high r=0: m = W-1: left = VAL0, right = 0
        if (VAL0 > bb) { bb = VAL0; bm = W - 1; }
        VAL1 = scA[1] + bb;
        if (lane <= 62 && tcell < nv1 - 1) {
          Dch[offCB[1] + tcell] = VAL1;
          SP[offCB[1] + tcell] = (uint8_t)bm;
        }
        SH11 = __shfl_down(VAL1, 1, 64);
        SH12 = __shfl_down(VAL1, 2, 64);
      }
      // ---------------- j = 2 (W = W0+2) ----------------
      {
        const int W = W0 + 2;
        float bb = SH11;  // m=0: 0 + VAL1(t+1)
        int bm = 0;
        {  // dyn-low m=1: diag1 + VAL0(t+2)
          float c = Dch[offT[1] + tc] + SH02;
          if (c > bb) { bb = c; bm = 1; }
        }
#pragma unroll
        for (int dm = 0; dm < 4; ++dm) {  // static-low m = 2+dm
          const int m = 2 + dm;
          float c = Dch[offT[m] + tc] + Dch[offPB[3 - dm] + tc + m + 1];
          if (c > bb) { bb = c; bm = m; }
        }
#pragma unroll
        for (int g = 0; g < 4; ++g) {
          if (g >= GHa) break;
          const int sl = 1024 + g * SGa + tc;
          float x = pvo[sl];
          if (x > bb) { bb = x; bm = pmo[sl]; }
        }
#pragma unroll
        for (int dr = 3; dr >= 0; --dr) {  // static-high r = 2+dr
          const int r = 2 + dr;
          const int m = W - 1 - r;  // = W0-1-dr
          float c = Dch[offPB[3 - dr] + tc] + Dch[offT[r] + tc + W - r];
          if (c > bb) { bb = c; bm = m; }
        }
        {  // dyn-high r=1: m = W-2 = W0: VAL0 + diag1(t+W-1)
          float c = VAL0 + Dch[offT[1] + tc + W - 1];
          if (c > bb) { bb = c; bm = W - 2; }
        }
        // dyn-high r=0: m = W-1: VAL1 + 0
        if (VAL1 > bb) { bb = VAL1; bm = W - 1; }
        VAL2 = scA[2] + bb;
        if (lane <= 61 && tcell < nv1 - 2) {
          Dch[offCB[2] + tcell] = VAL2;
          SP[offCB[2] + tcell] = (uint8_t)bm;
        }
        SH21 = __shfl_down(VAL2, 1, 64);
      }
      // ---------------- j = 3 (W = W0+3) ----------------
      {
        const int W = W0 + 3;
        float bb = SH21;  // m=0: 0 + VAL2(t+1)
        int bm = 0;
        {  // dyn-low m=1: diag1 + VAL1(t+2)
          float c = Dch[offT[1] + tc] + SH12;
          if (c > bb) { bb = c; bm = 1; }
        }
        {  // dyn-low m=2: diag2 + VAL0(t+3)
          float c = Dch[offT[2] + tc] + SH03;
          if (c > bb) { bb = c; bm = 2; }
        }
#pragma unroll
        for (int dm = 0; dm < 4; ++dm) {  // static-low m = 3+dm
          const int m = 3 + dm;
          float c = Dch[offT[m] + tc] + Dch[offPB[3 - dm] + tc + m + 1];
          if (c > bb) { bb = c; bm = m; }
        }
#pragma unroll
        for (int g = 0; g < 4; ++g) {
          if (g >= GHa) break;
          const int sl = 1536 + g * SGa + tc;
          float x = pvo[sl];
          if (x > bb) { bb = x; bm = pmo[sl]; }
        }
#pragma unroll
        for (int dr = 3; dr >= 0; --dr) {  // static-high r = 3+dr
          const int r = 3 + dr;
          const int m = W - 1 - r;  // = W0-1-dr
          float c = Dch[offPB[3 - dr] + tc] + Dch[offT[r] + tc + W - r];
          if (c > bb) { bb = c; bm = m; }
        }
        {  // dyn-high r=2: m = W-3 = W0: VAL0 + diag2(t+W-2)
          float c = VAL0 + Dch[offT[2] + tc + W - 2];
          if (c > bb) { bb = c; bm = W - 3; }
        }
        {  // dyn-high r=1: m = W-2 = W0+1: VAL1 + diag1(t+W-1)
          float c = VAL1 + Dch[offT[1] + tc + W - 1];
          if (c > bb) { bb = c; bm = W - 2; }
        }
        // dyn-high r=0: m = W-1: VAL2 + 0
        if (VAL2 > bb) { bb = VAL2; bm = W - 1; }
        VAL3 = scA[3] + bb;
        if (lane <= 60 && tcell < nv1 - 3) {
          Dch[offCB[3] + tcell] = VAL3;
          SP[offCB[3] + tcell] = (uint8_t)bm;
        }
      }
    }

    // ---- (b): partials for superstep s+1 (diags W0+4..W0+7) ----
    if (s < 64) run_b(W0, pb);

    asm volatile("s_waitcnt lgkmcnt(0)\n\ts_barrier" ::: "memory");
#pragma unroll
    for (int j = 0; j < 4; ++j) scA[j] = P4[j];
  }

  // Drain all SP stores (whole loop's worth) once, then barrier.
  asm volatile("s_waitcnt vmcnt(0) lgkmcnt(0)\n\ts_barrier" ::: "memory");
  uint8_t* spl = (uint8_t*)Dch;
  for (int idx = t; idx < 32896; idx += 1024) spl[idx] = SP[idx];
  asm volatile("s_waitcnt vmcnt(0) lgkmcnt(0)\n\ts_barrier" ::: "memory");
  if (t == 0) {
    int top = 0;
    stk[top++] = (0 << 16) | (n - 1);
    int cnt = 0;
    for (int step = 0; step < n - 1; ++step) {
      if (top > 0) {
        int ij = stk[--top];
        int ii = ij >> 16, jj = ij & 0xffff;
        out[b * n + cnt] = ii;
        out[Bb * n + b * n + cnt] = jj;
        ++cnt;
        int k = jj - ii;
        int s2 = ii + (int)spl[k * n - ((k * (k - 1)) >> 1) + ii];
        stk[top] = (ii << 16) | s2;
        if (s2 > ii) ++top;
        stk[top] = ((s2 + 1) << 16) | jj;
        if (jj > s2 + 1) ++top;
      }
    }
  }
}

// ---------------------------------------------------------------------------
// Launch
// ---------------------------------------------------------------------------
extern "C" void kernel_launch(void* const* d_in, const int* in_sizes, int n_in,
                              void* d_out, int out_size, void* d_ws,
                              size_t ws_size, hipStream_t stream) {
  const float* X = (const float*)d_in[0];     // [64,256,1024]
  const float* Wl = (const float*)d_in[2];    // [1024,1024]
  const float* bl = (const float*)d_in[3];    // [1024]
  const float* Wr = (const float*)d_in[4];
  const float* br = (const float*)d_in[5];
  const float* Wbil = (const float*)d_in[6];  // [1025,1025]
  const float* bbil = (const float*)d_in[7];  // scalar
  int* out = (int*)d_out;

  // workspace layout
  float* ws = (float*)d_ws;
  float* lefts = ws;                          // 16777216 f
  float* rights = lefts + 16777216;           // 16777216 f
  float* tmpA = rights + 16777216;            // 16777216 f
  float* scoresP = tmpA + 16777216;           // 4194304 f
  float* tmpb = scoresP + 4194304;            // 16384 f
  float* browp = tmpb + 16384;                // 1024 f
  float* bcolp = browp + 1024;                // 1024 f
  float* cornerp = bcolp + 1024;              // 4 f
  unsigned short* Wlrt = (unsigned short*)(cornerp + 4);  // 2 x 2M fp16
  unsigned short* Wct = Wlrt + 2LL * 2097152;             // 2 x 1M fp16
  uint8_t* SPp = (uint8_t*)(Wct + 2LL * 1048576);         // 64x32896 u8

  // weight splits (+ Wbil bias vectors)
  splitw_kernel<<<dim3(4096), 256, 0, stream>>>(Wl, 1024, Wlrt, 2097152);
  splitw_kernel<<<dim3(4096), 256, 0, stream>>>(Wr, 1024, Wlrt + 1048576,
                                                2097152);
  splitw_kernel<<<dim3(4096), 256, 0, stream>>>(Wbil, 1025, Wct, 1048576);
  bilvec_kernel<<<dim3(4), 256, 0, stream>>>(Wbil, browp, bcolp, cornerp);

  // fused lefts|rights GEMM: N=2048
  dim3 gLR(16, 128);
  gemm_mfma_kernel<true><<<gLR, 256, 0, stream>>>(X, Wlrt, 2097152LL, lefts,
                                                  rights, bl, br);

  colvec_kernel<<<dim3(16384), 64, 0, stream>>>(lefts, bcolp, cornerp, tmpb);

  dim3 gA(8, 128);
  gemm_mfma_kernel<false><<<gA, 256, 0, stream>>>(lefts, Wct, 1048576LL, tmpA,
                                                  tmpA, browp, browp);

  dim3 g3(2, 2, 64);
  gemmnt_mfma_kernel<<<g3, 256, 0, stream>>>(tmpA, rights, scoresP, tmpb,
                                             bbil);

  cky_kernel<<<dim3(Bb), dim3(1024), 0, stream>>>(scoresP, SPp, out);
}

// Round 4
// 865.201 us; speedup vs baseline: 1.4201x; 1.0908x over previous
//
#include <hip/hip_runtime.h>
#include <cstdint>

// ---------------------------------------------------------------------------
// ChartParser: span scores + per-batch CKY DP + backtrack.
// B=64, S=256, D=H=1024. Output: int32 [2][B][S] (lefts then rights).
// Round 12: GEMM pipeline rework (cky unchanged from round 11):
//  - gemm_mfma: B staged via global_load_lds width=16 with PRE-SWIZZLED
//    per-lane global source (LDS dest linear in lane, swizzle folded into
//    source k-chunk = c ^ phi(r)); B double-buffered (2x16KB), DMA for
//    step k+1 issued during MFMA of step k; A registers prefetched one
//    step ahead. Barriers are raw "s_waitcnt lgkmcnt(0); s_barrier";
//    the only vmcnt(0) drain is at the consume point (mid-barrier).
//    LDS 48KB -> still 3 blocks/CU. Numerically bit-identical.
//  - gemmnt: A-register prefetch one step ahead + raw barriers.
// ---------------------------------------------------------------------------

#define Bb 64
#define Ss 256
#define Dd 1024
#define Hh 1024

typedef __attribute__((ext_vector_type(8))) _Float16 f16x8;
typedef __attribute__((ext_vector_type(4))) float f32x4;

// x = h + l + delta, |delta| <= 2^-22 |x| (fp16 RNE twice)
__device__ __forceinline__ void split2(float x, unsigned short& h,
                                       unsigned short& l) {
  _Float16 hh = (_Float16)x;
  _Float16 ll = (_Float16)(x - (float)hh);
  h = __builtin_bit_cast(unsigned short, hh);
  l = __builtin_bit_cast(unsigned short, ll);
}

// async global->LDS, 16B per lane; LDS dest = uniform base + lane*16
__device__ __forceinline__ void gl_lds16(const void* g, void* l) {
  __builtin_amdgcn_global_load_lds(
      (const __attribute__((address_space(1))) void*)g,
      (__attribute__((address_space(3))) void*)l, 16, 0, 0);
}

// ---------------------------------------------------------------------------
// Weight split+transpose: W fp32 [1024 k-rows, ld ldw] -> O fp16 [n][k],
// limb planes at +0, +plane.
// ---------------------------------------------------------------------------
__global__ __launch_bounds__(256) void splitw_kernel(
    const float* __restrict__ W, int ldw, unsigned short* __restrict__ O,
    long long plane) {
  int idx = blockIdx.x * 256 + threadIdx.x;  // n*1024 + k
  int n = idx >> 10, k = idx & 1023;
  float x = W[(long long)k * ldw + n];
  unsigned short h, l;
  split2(x, h, l);
  O[idx] = h;
  O[plane + idx] = l;
}

// Extract Wbil's bias row / col / corner.
__global__ __launch_bounds__(256) void bilvec_kernel(
    const float* __restrict__ Wbil, float* __restrict__ brow,
    float* __restrict__ bcol, float* __restrict__ corner) {
  int i = blockIdx.x * 256 + threadIdx.x;  // 0..1023
  brow[i] = Wbil[1024 * 1025 + i];
  bcol[i] = Wbil[i * 1025 + 1024];
  if (i == 0) corner[0] = Wbil[1024 * 1025 + 1024];
}

__device__ __forceinline__ void pack8(char* dst, const unsigned short* v) {
  uint4 u;
  u.x = (unsigned)v[0] | ((unsigned)v[1] << 16);
  u.y = (unsigned)v[2] | ((unsigned)v[3] << 16);
  u.z = (unsigned)v[4] | ((unsigned)v[5] << 16);
  u.w = (unsigned)v[6] | ((unsigned)v[7] << 16);
  *(uint4*)dst = u;
}

// split 16 fp32 -> 2x16 fp16 limbs, store (swizzled) to 2 LDS planes
__device__ __forceinline__ void split_store16f(const float* xs, char* lds,
                                               int base, int wa0, int wa1) {
  unsigned short hs[16], ls[16];
#pragma unroll
  for (int i = 0; i < 16; ++i) split2(xs[i], hs[i], ls[i]);
  pack8(&lds[base + wa0], hs);
  pack8(&lds[base + wa1], hs + 8);
  pack8(&lds[base + 8192 + wa0], ls);
  pack8(&lds[base + 8192 + wa1], ls + 8);
}

// 4-product accumulate for one nf column: (ah+al)x(bh+bl), all kept
#define MFMA4(afv, bh, blv, accs, nf)                                        \
  {                                                                          \
    _Pragma("unroll") for (int mf = 0; mf < 4; ++mf) accs[mf][nf] =          \
        __builtin_amdgcn_mfma_f32_16x16x32_f16(afv[0][mf], bh,               \
                                               accs[mf][nf], 0, 0, 0);       \
    _Pragma("unroll") for (int mf = 0; mf < 4; ++mf) accs[mf][nf] =          \
        __builtin_amdgcn_mfma_f32_16x16x32_f16(afv[0][mf], blv,              \
                                               accs[mf][nf], 0, 0, 0);       \
    _Pragma("unroll") for (int mf = 0; mf < 4; ++mf) accs[mf][nf] =          \
        __builtin_amdgcn_mfma_f32_16x16x32_f16(afv[1][mf], bh,               \
                                               accs[mf][nf], 0, 0, 0);       \
    _Pragma("unroll") for (int mf = 0; mf < 4; ++mf) accs[mf][nf] =          \
        __builtin_amdgcn_mfma_f32_16x16x32_f16(afv[1][mf], blv,              \
                                               accs[mf][nf], 0, 0, 0);       \
  }

// ---------------------------------------------------------------------------
// MFMA GEMM (NN): out = act(A[M,1024]_fp32 * Bsp + bias). Bsp pre-split fp16
// [n][k], limb planes at stride bplane. Tile 128x128, BK=32, 256 threads,
// wave-tile 64x64 (4x4 frags of mfma_f32_16x16x32_f16).
// LDS 48KB: Ah@0, Al@8192, Bbuf0@16384, Bbuf1@32768 (each: h 8KB + l 8KB).
// 16B-chunk XOR swizzle phi(r)=((r>>1)^(r>>3))&3; for B the swizzle is
// folded into the per-lane GLOBAL source address (LDS dest linear).
// If n0 >= 1024 the block writes C1/bias1 at col-1024 (fused dual output).
// ---------------------------------------------------------------------------
template <bool LEAKY>
__global__ __launch_bounds__(256, 3) void gemm_mfma_kernel(
    const float* __restrict__ A, const unsigned short* __restrict__ Bsp,
    long long bplane, float* __restrict__ C0, float* __restrict__ C1,
    const float* __restrict__ bias0, const float* __restrict__ bias1) {
  const int m0 = blockIdx.y * 128;
  const int n0 = blockIdx.x * 128;
  __shared__ __align__(16) char lds[49152];
  const int t = threadIdx.x;
  const int L = t & 63, w = t >> 6, q = L >> 4, l15 = L & 15;

  const int ar = t >> 1, ah = t & 1;
  const float* aptr = A + (long long)(m0 + ar) * 1024 + ah * 16;
  const int phiA = ((ar >> 1) ^ (ar >> 3)) & 3;
  const int wa0 = ar * 64 + (((2 * ah + 0) ^ phiA) << 4);
  const int wa1 = ar * 64 + (((2 * ah + 1) ^ phiA) << 4);

  int offA0[4], offB0[4];
#pragma unroll
  for (int f = 0; f < 4; ++f) {
    int rowa = ((w & 1) << 6) + (f << 4) + l15;
    offA0[f] = rowa * 64 + ((q ^ (((rowa >> 1) ^ (rowa >> 3)) & 3)) << 4);
    int rowb = ((w >> 1) << 6) + (f << 4) + l15;
    offB0[f] = rowb * 64 + ((q ^ (((rowb >> 1) ^ (rowb >> 3)) & 3)) << 4);
  }

  // B DMA setup: wave w issues 4 x 1KB (16 rows each); lane covers
  // (row = base + lane/4, chunk c = lane&3); source k-chunk = c ^ phi(row).
  const int lrow = L >> 2, lchk = L & 3;
  const unsigned short* bsrc[4];
  int bldso[4];
#pragma unroll
  for (int i = 0; i < 4; ++i) {
    int O = ((w << 2) + i) << 10;  // 0..15360, within 16KB B tile
    int s2 = O >> 13;              // limb plane
    int r = ((O & 8191) >> 6) + lrow;
    int phi = ((r >> 1) ^ (r >> 3)) & 3;
    bsrc[i] = Bsp + (long long)s2 * bplane + (long long)(n0 + r) * 1024 +
              ((lchk ^ phi) << 3);
    bldso[i] = O;
  }

  f32x4 acc[4][4];
#pragma unroll
  for (int i = 0; i < 4; ++i)
#pragma unroll
    for (int j = 0; j < 4; ++j) acc[i][j] = (f32x4){0.f, 0.f, 0.f, 0.f};

  // prologue: issue B DMA (k0=0) into buf0; load A regs (k0=0)
#pragma unroll
  for (int i = 0; i < 4; ++i) gl_lds16(bsrc[i], &lds[16384 + bldso[i]]);
  float4 a0 = *(const float4*)(aptr + 0);
  float4 a1 = *(const float4*)(aptr + 4);
  float4 a2 = *(const float4*)(aptr + 8);
  float4 a3 = *(const float4*)(aptr + 12);

  int cur = 0;
  for (int k0 = 0; k0 < 1024; k0 += 32) {
    // P1: convert+write A (consumes prefetched a0..a3)
    {
      float xs[16] = {a0.x, a0.y, a0.z, a0.w, a1.x, a1.y, a1.z, a1.w,
                      a2.x, a2.y, a2.z, a2.w, a3.x, a3.y, a3.z, a3.w};
      split_store16f(xs, lds, 0, wa0, wa1);
    }
    // mid barrier: B[cur] DMA landed + A writes visible to all waves
    asm volatile("s_waitcnt vmcnt(0) lgkmcnt(0)\n\ts_barrier" ::: "memory");
    // P2: issue next step's loads first (hidden under MFMA), then compute
    if (k0 < 992) {
      a0 = *(const float4*)(aptr + k0 + 32);
      a1 = *(const float4*)(aptr + k0 + 36);
      a2 = *(const float4*)(aptr + k0 + 40);
      a3 = *(const float4*)(aptr + k0 + 44);
      const int bn = 16384 + ((cur ^ 1) << 14);
#pragma unroll
      for (int i = 0; i < 4; ++i)
        gl_lds16(bsrc[i] + k0 + 32, &lds[bn + bldso[i]]);
    }
    const int bb = 16384 + (cur << 14);
    f16x8 af[2][4];
#pragma unroll
    for (int s = 0; s < 2; ++s)
#pragma unroll
      for (int f = 0; f < 4; ++f)
        af[s][f] = *(const f16x8*)&lds[s * 8192 + offA0[f]];
#pragma unroll
    for (int nf = 0; nf < 4; ++nf) {
      f16x8 bh = *(const f16x8*)&lds[bb + offB0[nf]];
      f16x8 bl = *(const f16x8*)&lds[bb + 8192 + offB0[nf]];
      MFMA4(af, bh, bl, acc, nf);
    }
    // end barrier: LDS reads done before next P1 overwrites A; DMA stays
    // in flight (no vmcnt drain).
    asm volatile("s_waitcnt lgkmcnt(0)\n\ts_barrier" ::: "memory");
    cur ^= 1;
  }

  const bool isR = (n0 >= 1024);
  float* Co = isR ? C1 : C0;
  const float* bp = isR ? bias1 : bias0;
  const int nc0 = n0 & 1023;
#pragma unroll
  for (int nf = 0; nf < 4; ++nf) {
    int col = nc0 + ((w >> 1) << 6) + (nf << 4) + l15;
    float bz = bp[col];
#pragma unroll
    for (int mf = 0; mf < 4; ++mf) {
#pragma unroll
      for (int r = 0; r < 4; ++r) {
        int row = m0 + ((w & 1) << 6) + (mf << 4) + (q << 2) + r;
        float x = acc[mf][nf][r] + bz;
        if (LEAKY) x = (x > 0.f) ? x : 0.1f * x;
        Co[(long long)row * 1024 + col] = x;
      }
    }
  }
}

// ---------------------------------------------------------------------------
// Batched NT GEMM on MFMA: C[b] = tmpA[b] * rights[b]^T + rowAdd + scal.
// Both operands fp32, split in-kernel to fp16x2. Tile 128x128, grid (2,2,64).
// Round 12: A-register prefetch one K-step ahead + raw barriers (no vmcnt
// drain at barriers; compiler handles reg-load waits).
// ---------------------------------------------------------------------------
__global__ __launch_bounds__(256, 3) void gemmnt_mfma_kernel(
    const float* __restrict__ A, const float* __restrict__ B,
    float* __restrict__ C, const float* __restrict__ rowAdd,
    const float* __restrict__ scal) {
  const int bz = blockIdx.z;
  A += (long long)bz * 256 * 1024;
  B += (long long)bz * 256 * 1024;
  C += (long long)bz * 256 * 256;
  const int m0 = blockIdx.y * 128;
  const int n0 = blockIdx.x * 128;
  __shared__ __align__(16) char lds[32768];
  const int t = threadIdx.x;
  const int L = t & 63, w = t >> 6, q = L >> 4, l15 = L & 15;

  const int ar = t >> 1, ah = t & 1;
  const float* aptr = A + (long long)(m0 + ar) * 1024 + ah * 16;
  const float* bptr = B + (long long)(n0 + ar) * 1024 + ah * 16;
  const int phiA = ((ar >> 1) ^ (ar >> 3)) & 3;
  const int wa0 = ar * 64 + (((2 * ah + 0) ^ phiA) << 4);
  const int wa1 = ar * 64 + (((2 * ah + 1) ^ phiA) << 4);

  int offA0[4], offB0[4];
#pragma unroll
  for (int f = 0; f < 4; ++f) {
    int rowa = ((w & 1) << 6) + (f << 4) + l15;
    offA0[f] = rowa * 64 + ((q ^ (((rowa >> 1) ^ (rowa >> 3)) & 3)) << 4);
    int rowb = ((w >> 1) << 6) + (f << 4) + l15;
    offB0[f] =
        16384 + rowb * 64 + ((q ^ (((rowb >> 1) ^ (rowb >> 3)) & 3)) << 4);
  }

  f32x4 acc[4][4];
#pragma unroll
  for (int i = 0; i < 4; ++i)
#pragma unroll
    for (int j = 0; j < 4; ++j) acc[i][j] = (f32x4){0.f, 0.f, 0.f, 0.f};

  // prologue: load A+B regs for k0=0
  float4 a0 = *(const float4*)(aptr + 0);
  float4 a1 = *(const float4*)(aptr + 4);
  float4 a2 = *(const float4*)(aptr + 8);
  float4 a3 = *(const float4*)(aptr + 12);
  float4 b0 = *(const float4*)(bptr + 0);
  float4 b1 = *(const float4*)(bptr + 4);
  float4 b2 = *(const float4*)(bptr + 8);
  float4 b3 = *(const float4*)(bptr + 12);

  for (int k0 = 0; k0 < 1024; k0 += 32) {
    {
      float xs[16] = {a0.x, a0.y, a0.z, a0.w, a1.x, a1.y, a1.z, a1.w,
                      a2.x, a2.y, a2.z, a2.w, a3.x, a3.y, a3.z, a3.w};
      split_store16f(xs, lds, 0, wa0, wa1);
      float ys[16] = {b0.x, b0.y, b0.z, b0.w, b1.x, b1.y, b1.z, b1.w,
                      b2.x, b2.y, b2.z, b2.w, b3.x, b3.y, b3.z, b3.w};
      split_store16f(ys, lds, 16384, wa0, wa1);
    }
    asm volatile("s_waitcnt lgkmcnt(0)\n\ts_barrier" ::: "memory");
    if (k0 < 992) {
      a0 = *(const float4*)(aptr + k0 + 32);
      a1 = *(const float4*)(aptr + k0 + 36);
      a2 = *(const float4*)(aptr + k0 + 40);
      a3 = *(const float4*)(aptr + k0 + 44);
      b0 = *(const float4*)(bptr + k0 + 32);
      b1 = *(const float4*)(bptr + k0 + 36);
      b2 = *(const float4*)(bptr + k0 + 40);
      b3 = *(const float4*)(bptr + k0 + 44);
    }
    f16x8 af[2][4];
#pragma unroll
    for (int s = 0; s < 2; ++s)
#pragma unroll
      for (int f = 0; f < 4; ++f)
        af[s][f] = *(const f16x8*)&lds[s * 8192 + offA0[f]];
#pragma unroll
    for (int nf = 0; nf < 4; ++nf) {
      f16x8 bh = *(const f16x8*)&lds[offB0[nf]];
      f16x8 bl = *(const f16x8*)&lds[8192 + offB0[nf]];
      MFMA4(af, bh, bl, acc, nf);
    }
    asm volatile("s_waitcnt lgkmcnt(0)\n\ts_barrier" ::: "memory");
  }

  const float sc_add = scal[0];
#pragma unroll
  for (int mf = 0; mf < 4; ++mf) {
#pragma unroll
    for (int r = 0; r < 4; ++r) {
      int row = m0 + ((w & 1) << 6) + (mf << 4) + (q << 2) + r;
      float radd = sc_add + rowAdd[(long long)bz * 256 + row];
#pragma unroll
      for (int nf = 0; nf < 4; ++nf) {
        int col = n0 + ((w >> 1) << 6) + (nf << 4) + l15;
        C[(long long)row * 256 + col] = acc[mf][nf][r] + radd;
      }
    }
  }
}

// ---------------------------------------------------------------------------
// tmpb[i] = dot(lefts[i,:], Wbil[0:H, H]) + Wbil[H,H].  One wave per row.
// ---------------------------------------------------------------------------
__global__ __launch_bounds__(64) void colvec_kernel(
    const float* __restrict__ lefts, const float* __restrict__ bcol,
    const float* __restrict__ corner, float* __restrict__ tmpb) {
  int row = blockIdx.x;
  int lane = threadIdx.x;
  const float* a = lefts + (long long)row * Hh;
  float s = 0.f;
#pragma unroll
  for (int h = lane; h < Hh; h += 64) s = fmaf(a[h], bcol[h], s);
#pragma unroll
  for (int off = 32; off > 0; off >>= 1) s += __shfl_down(s, off, 64);
  if (lane == 0) tmpb[row] = s + corner[0];
}

// ---------------------------------------------------------------------------
// CKY + backtrack. One block per batch, 1024 threads. Chart in LDS, packed
// triangular diag-major. FOUR diagonals per barrier (round 11, unchanged).
// ---------------------------------------------------------------------------
__global__ __launch_bounds__(1024) void cky_kernel(
    const float* __restrict__ scores,  // [64][256][256]
    uint8_t* __restrict__ Sws,         // [64][32896] packed triangular
    int* __restrict__ out)             // [2][64][256] int32
{
  const int b = blockIdx.x;
  const int t = threadIdx.x;
  const int n = Ss;
  const float* sc = scores + (long long)b * n * n;
  uint8_t* SP = Sws + (long long)b * 32896;

  __shared__ float Dch[32896];
  __shared__ float pv[2][2048];
  __shared__ uint8_t pmv[2][2048];
  __shared__ int stk[256];

  // offsets of tiny diags 0..9 (compile-time constants)
  const int offT[10] = {0,    256,  511,  765,  1018,
                        1270, 1521, 1771, 2020, 2268};

  if (t < n) {
    out[b * n + t] = 0;
    out[Bb * n + b * n + t] = 0;
    Dch[t] = 0.f;  // diag 0
  }

  // prologue score prefetch (diags 1..9 at cell t, clamped addresses)
  float PS[10];
  PS[0] = 0.f;
#pragma unroll
  for (int w = 1; w <= 9; ++w) {
    int ic = t;
    if (ic > 255 - w) ic = 255 - w;
    PS[w] = sc[ic * 257 + w];
  }
  asm volatile("s_waitcnt lgkmcnt(0)\n\ts_barrier" ::: "memory");

  // prologue: diags 1..9, one barrier each (generic m-scan, ascending,
  // strict > = first-max)
#pragma unroll
  for (int w = 1; w <= 9; ++w) {
    const int nv = n - w;
    if (t < nv) {
      float bb = Dch[offT[w - 1] + t + 1];  // m=0: 0 + right
      int bm = 0;
#pragma unroll
      for (int m = 1; m < 9; ++m) {
        if (m >= w) break;
        float c = Dch[offT[m] + t] + Dch[offT[w - 1 - m] + t + m + 1];
        if (c > bb) { bb = c; bm = m; }
      }
      const int off = w * 256 - ((w * (w - 1)) >> 1);
      Dch[off + t] = PS[w] + bb;
      SP[off + t] = (uint8_t)bm;
    }
    asm volatile("s_waitcnt lgkmcnt(0)\n\ts_barrier" ::: "memory");
  }

  // generic (b): group partials for superstep with base W0b+4 (4 diags).
  // Covers m in [jb+4, W0b-1] (left/right spans are diags <= W0b-1, i.e.
  // >= 1 barrier old when run inside superstep W0b). Writes pv/pmv[pbuf].
  auto run_b = [&](int W0b, int pbuf) {
    const int cnv = n - W0b - 4;  // cells of consumer's first diag
    int jb, gb, u, delta, lgGHL, SLOTG;
    if (cnv > 128) {  // RA: 2 groups/diag, T=128, slices (u, u+128)
      const int p = t >> 7;
      jb = 3 - (p >> 1);
      gb = 1 - (p & 1);
      u = t & 127;
      delta = 128;
      lgGHL = 1;
      SLOTG = 256;
    } else {  // RB/RC: 4 groups/diag, T=64
      const int wid = t >> 6;
      jb = 3 - (wid >> 2);
      gb = 3 - (wid & 3);
      u = t & 63;
      delta = (cnv > 64) ? 64 : 0;
      lgGHL = 2;
      SLOTG = 128;
    }
    const int Wb = W0b + 4 + jb;
    const int nvb = n - Wb;
    int cnt = W0b - jb - 4;
    if (cnt < 0) cnt = 0;
    const int per = (cnt + (1 << lgGHL) - 1) >> lgGHL;
    const int mlo = jb + 4;
    int ml = mlo + gb * per;
    int mh = mlo + cnt;
    {
      int e = ml + per;
      if (e < mh) mh = e;
    }
    float b0 = -3.0e38f, b1 = -3.0e38f;
    int m0i = ml, m1i = ml;
    if (u < nvb && ml < mh) {
      int al = ml * n - ((ml * (ml - 1)) >> 1) + u;
      const int kr = Wb - 1 - ml;
      int ar = kr * n - ((kr * (kr - 1)) >> 1) + u + ml + 1;
      int dl = n - ml;
      int dr = n - Wb + ml + 1;
      if (delta) {
#pragma unroll 2
        for (int m = ml; m < mh; ++m) {
          float l0 = Dch[al], l1 = Dch[al + delta];  // -> ds_read2_b32
          float r0 = Dch[ar], r1 = Dch[ar + delta];  // -> ds_read2_b32
          float c0 = l0 + r0, c1 = l1 + r1;
          if (c0 > b0) { b0 = c0; m0i = m; }  // strict > = first max
          if (c1 > b1) { b1 = c1; m1i = m; }
          al += dl;
          ar -= dr;
          --dl;
          ++dr;
        }
      } else {
#pragma unroll 4
        for (int m = ml; m < mh; ++m) {
          float c = Dch[al] + Dch[ar];
          if (c > b0) { b0 = c; m0i = m; }
          al += dl;
          ar -= dr;
          --dl;
          ++dr;
        }
      }
    }
    const int slot = jb * 512 + gb * SLOTG + u;
    pv[pbuf][slot] = b0;
    pmv[pbuf][slot] = (uint8_t)m0i;
    if (delta) {
      pv[pbuf][slot + delta] = b1;
      pmv[pbuf][slot + delta] = (uint8_t)m1i;
    }
  };

  // prologue (b): partials for s=3 (diags 10..13), "s=2" role -> pv[0]
  run_b(6, 0);
  asm volatile("s_waitcnt lgkmcnt(0)\n\ts_barrier" ::: "memory");

  // (a)-band geometry: wave wv covers cells 61*wv + lane (3-lane overlap)
  const int wv = t >> 6, lane = t & 63;
  const int tcell = 61 * wv + lane;

  // seed scores for s=3 (diags 10..13)
  float scA[4];
#pragma unroll
  for (int j = 0; j < 4; ++j) {
    const int Wn = 10 + j;
    int ic = tcell;
    if (ic > 255 - Wn) ic = 255 - Wn;
    if (ic < 0) ic = 0;
    scA[j] = sc[ic * 257 + Wn];
  }

  for (int s = 3; s <= 64; ++s) {
    const int W0 = 4 * s - 2;
    const int nv1 = n - W0;
    const int pb = s & 1, po = pb ^ 1;
    const int nb = (nv1 + 60) / 61;

    // prefetch next superstep's scores (diags W0+4..W0+7)
    float P4[4] = {0.f, 0.f, 0.f, 0.f};
    if (s < 64 && wv < nb) {
#pragma unroll
      for (int j = 0; j < 4; ++j) {
        const int Wn = W0 + 4 + j;
        int ic = tcell;
        if (ic > 255 - Wn) ic = 255 - Wn;
        if (ic < 0) ic = 0;
        P4[j] = sc[ic * 257 + Wn];
      }
    }

    // ---- (a): finalize diags W0..W0+3 ----
    if (wv < nb) {
      const int tc = (tcell < nv1) ? tcell : (nv1 - 1);  // clamped (safe)
      const float* pvo = pv[po];
      const uint8_t* pmo = pmv[po];
      int GHa, SGa;
      if (nv1 > 128) { GHa = 2; SGa = 256; } else { GHa = 4; SGa = 128; }
      int offPB[4], offCB[4];
#pragma unroll
      for (int d = 0; d < 4; ++d) {
        const int dg = W0 - 4 + d;
        offPB[d] = dg * 256 - ((dg * (dg - 1)) >> 1);
        const int cg = W0 + d;
        offCB[d] = cg * 256 - ((cg * (cg - 1)) >> 1);
      }
      float VAL0, VAL1, VAL2, VAL3;
      float SH01, SH02, SH03, SH11, SH12, SH21;
      // ---------------- j = 0 (W = W0) ----------------
      {
        const int W = W0;
        float bb = Dch[offPB[3] + tc + 1];  // m=0: 0 + prev-batch diag W-1
        int bm = 0;
#pragma unroll
        for (int dm = 1; dm < 4; ++dm) {  // static-low m = dm
          const int m = dm;
          float c = Dch[offT[m] + tc] + Dch[offPB[3 - dm] + tc + m + 1];
          if (c > bb) { bb = c; bm = m; }
        }
#pragma unroll
        for (int g = 0; g < 4; ++g) {  // partials [4, W0-5]
          if (g >= GHa) break;
          const int sl = g * SGa + tc;
          float x = pvo[sl];
          if (x > bb) { bb = x; bm = pmo[sl]; }
        }
#pragma unroll
        for (int dr = 3; dr >= 0; --dr) {  // static-high m = W0-1-dr asc
          const int r = dr;
          const int m = W - 1 - r;
          float right = (r == 0) ? 0.f : Dch[offT[r] + tc + W - r];
          float c = Dch[offPB[3 - dr] + tc] + right;
          if (c > bb) { bb = c; bm = m; }
        }
        VAL0 = scA[0] + bb;
        if (tcell < nv1) {
          Dch[offCB[0] + tcell] = VAL0;
          SP[offCB[0] + tcell] = (uint8_t)bm;
        }
        SH01 = __shfl_down(VAL0, 1, 64);
        SH02 = __shfl_down(VAL0, 2, 64);
        SH03 = __shfl_down(VAL0, 3, 64);
      }
      // ---------------- j = 1 (W = W0+1) ----------------
      {
        const int W = W0 + 1;
        float bb = SH01;  // m=0: 0 + VAL0(t+1)
        int bm = 0;
#pragma unroll
        for (int dm = 0; dm < 4; ++dm) {  // static-low m = 1+dm
          const int m = 1 + dm;
          float c = Dch[offT[m] + tc] + Dch[offPB[3 - dm] + tc + m + 1];
          if (c > bb) { bb = c; bm = m; }
        }
#pragma unroll
        for (int g = 0; g < 4; ++g) {
          if (g >= GHa) break;
          const int sl = 512 + g * SGa + tc;
          float x = pvo[sl];
          if (x > bb) { bb = x; bm = pmo[sl]; }
        }
#pragma unroll
        for (int dr = 3; dr >= 0; --dr) {  // static-high r = 1+dr
          const int r = 1 + dr;
          const int m = W - 1 - r;  // = W0-1-dr, ascending
          float c = Dch[offPB[3 - dr] + tc] + Dch[offT[r] + tc + W - r];
          if (c > bb) { bb = c; bm = m; }
        }
        // dyn-high r=0: m = W-1: left = VAL0, right = 0
        if (VAL0 > bb) { bb = VAL0; bm = W - 1; }
        VAL1 = scA[1] + bb;
        if (lane <= 62 && tcell < nv1 - 1) {
          Dch[offCB[1] + tcell] = VAL1;
          SP[offCB[1] + tcell] = (uint8_t)bm;
        }
        SH11 = __shfl_down(VAL1, 1, 64);
        SH12 = __shfl_down(VAL1, 2, 64);
      }
      // ---------------- j = 2 (W = W0+2) ----------------
      {
        const int W = W0 + 2;
        float bb = SH11;  // m=0: 0 + VAL1(t+1)
        int bm = 0;
        {  // dyn-low m=1: diag1 + VAL0(t+2)
          float c = Dch[offT[1] + tc] + SH02;
          if (c > bb) { bb = c; bm = 1; }
        }
#pragma unroll
        for (int dm = 0; dm < 4; ++dm) {  // static-low m = 2+dm
          const int m = 2 + dm;
          float c = Dch[offT[m] + tc] + Dch[offPB[3 - dm] + tc + m + 1];
          if (c > bb) { bb = c; bm = m; }
        }
#pragma unroll
        for (int g = 0; g < 4; ++g) {
          if (g >= GHa) break;
          const int sl = 1024 + g * SGa + tc;
          float x = pvo[sl];
          if (x > bb) { bb = x; bm = pmo[sl]; }
        }
#pragma unroll
        for (int dr = 3; dr >= 0; --dr) {  // static-high r = 2+dr
          const int r = 2 + dr;
          const int m = W - 1 - r;  // = W0-1-dr
          float c = Dch[offPB[3 - dr] + tc] + Dch[offT[r] + tc + W - r];
          if (c > bb) { bb = c; bm = m; }
        }
        {  // dyn-high r=1: m = W-2 = W0: VAL0 + diag1(t+W-1)
          float c = VAL0 + Dch[offT[1] + tc + W - 1];
          if (c > bb) { bb = c; bm = W - 2; }
        }
        // dyn-high r=0: m = W-1: VAL1 + 0
        if (VAL1 > bb) { bb = VAL1; bm = W - 1; }
        VAL2 = scA[2] + bb;
        if (lane <= 61 && tcell < nv1 - 2) {
          Dch[offCB[2] + tcell] = VAL2;
          SP[offCB[2] + tcell] = (uint8_t)bm;
        }
        SH21 = __shfl_down(VAL2, 1, 64);
      }
      // ---------------- j = 3 (W = W0+3) ----------------
      {
        const int W = W0 + 3;
        float bb = SH21;  // m=0: 0 + VAL2(t+1)
        int bm = 0;
        {  // dyn-low m=1: diag1 + VAL1(t+2)
          float c = Dch[offT[1] + tc] + SH12;
          if (c > bb) { bb = c; bm = 1; }
        }
        {  // dyn-low m=2: diag2 + VAL0(t+3)
          float c = Dch[offT[2] + tc] + SH03;
          if (c > bb) { bb = c; bm = 2; }
        }
#pragma unroll
        for (int dm = 0; dm < 4; ++dm) {  // static-low m = 3+dm
          const int m = 3 + dm;
          float c = Dch[offT[m] + tc] + Dch[offPB[3 - dm] + tc + m + 1];
          if (c > bb) { bb = c; bm = m; }
        }
#pragma unroll
        for (int g = 0; g < 4; ++g) {
          if (g >= GHa) break;
          const int sl = 1536 + g * SGa + tc;
          float x = pvo[sl];
          if (x > bb) { bb = x; bm = pmo[sl]; }
        }
#pragma unroll
        for (int dr = 3; dr >= 0; --dr) {  // static-high r = 3+dr
          const int r = 3 + dr;
          const int m = W - 1 - r;  // = W0-1-dr
          float c = Dch[offPB[3 - dr] + tc] + Dch[offT[r] + tc + W - r];
          if (c > bb) { bb = c; bm = m; }
        }
        {  // dyn-high r=2: m = W-3 = W0: VAL0 + diag2(t+W-2)
          float c = VAL0 + Dch[offT[2] + tc + W - 2];
          if (c > bb) { bb = c; bm = W - 3; }
        }
        {  // dyn-high r=1: m = W-2 = W0+1: VAL1 + diag1(t+W-1)
          float c = VAL1 + Dch[offT[1] + tc + W - 1];
          if (c > bb) { bb = c; bm = W - 2; }
        }
        // dyn-high r=0: m = W-1: VAL2 + 0
        if (VAL2 > bb) { bb = VAL2; bm = W - 1; }
        VAL3 = scA[3] + bb;
        if (lane <= 60 && tcell < nv1 - 3) {
          Dch[offCB[3] + tcell] = VAL3;
          SP[offCB[3] + tcell] = (uint8_t)bm;
        }
      }
    }

    // ---- (b): partials for superstep s+1 (diags W0+4..W0+7) ----
    if (s < 64) run_b(W0, pb);

    asm volatile("s_waitcnt lgkmcnt(0)\n\ts_barrier" ::: "memory");
#pragma unroll
    for (int j = 0; j < 4; ++j) scA[j] = P4[j];
  }

  // Drain all SP stores (whole loop's worth) once, then barrier.
  asm volatile("s_waitcnt vmcnt(0) lgkmcnt(0)\n\ts_barrier" ::: "memory");
  uint8_t* spl = (uint8_t*)Dch;
  for (int idx = t; idx < 32896; idx += 1024) spl[idx] = SP[idx];
  asm volatile("s_waitcnt vmcnt(0) lgkmcnt(0)\n\ts_barrier" ::: "memory");
  if (t == 0) {
    int top = 0;
    stk[top++] = (0 << 16) | (n - 1);
    int cnt = 0;
    for (int step = 0; step < n - 1; ++step) {
      if (top > 0) {
        int ij = stk[--top];
        int ii = ij >> 16, jj = ij & 0xffff;
        out[b * n + cnt] = ii;
        out[Bb * n + b * n + cnt] = jj;
        ++cnt;
        int k = jj - ii;
        int s2 = ii + (int)spl[k * n - ((k * (k - 1)) >> 1) + ii];
        stk[top] = (ii << 16) | s2;
        if (s2 > ii) ++top;
        stk[top] = ((s2 + 1) << 16) | jj;
        if (jj > s2 + 1) ++top;
      }
    }
  }
}

// ---------------------------------------------------------------------------
// Launch
// ---------------------------------------------------------------------------
extern "C" void kernel_launch(void* const* d_in, const int* in_sizes, int n_in,
                              void* d_out, int out_size, void* d_ws,
                              size_t ws_size, hipStream_t stream) {
  const float* X = (const float*)d_in[0];     // [64,256,1024]
  const float* Wl = (const float*)d_in[2];    // [1024,1024]
  const float* bl = (const float*)d_in[3];    // [1024]
  const float* Wr = (const float*)d_in[4];
  const float* br = (const float*)d_in[5];
  const float* Wbil = (const float*)d_in[6];  // [1025,1025]
  const float* bbil = (const float*)d_in[7];  // scalar
  int* out = (int*)d_out;

  // workspace layout
  float* ws = (float*)d_ws;
  float* lefts = ws;                          // 16777216 f
  float* rights = lefts + 16777216;           // 16777216 f
  float* tmpA = rights + 16777216;            // 16777216 f
  float* scoresP = tmpA + 16777216;           // 4194304 f
  float* tmpb = scoresP + 4194304;            // 16384 f
  float* browp = tmpb + 16384;                // 1024 f
  float* bcolp = browp + 1024;                // 1024 f
  float* cornerp = bcolp + 1024;              // 4 f
  unsigned short* Wlrt = (unsigned short*)(cornerp + 4);  // 2 x 2M fp16
  unsigned short* Wct = Wlrt + 2LL * 2097152;             // 2 x 1M fp16
  uint8_t* SPp = (uint8_t*)(Wct + 2LL * 1048576);         // 64x32896 u8

  // weight splits (+ Wbil bias vectors)
  splitw_kernel<<<dim3(4096), 256, 0, stream>>>(Wl, 1024, Wlrt, 2097152);
  splitw_kernel<<<dim3(4096), 256, 0, stream>>>(Wr, 1024, Wlrt + 1048576,
                                                2097152);
  splitw_kernel<<<dim3(4096), 256, 0, stream>>>(Wbil, 1025, Wct, 1048576);
  bilvec_kernel<<<dim3(4), 256, 0, stream>>>(Wbil, browp, bcolp, cornerp);

  // fused lefts|rights GEMM: N=2048
  dim3 gLR(16, 128);
  gemm_mfma_kernel<true><<<gLR, 256, 0, stream>>>(X, Wlrt, 2097152LL, lefts,
                                                  rights, bl, br);

  colvec_kernel<<<dim3(16384), 64, 0, stream>>>(lefts, bcolp, cornerp, tmpb);

  dim3 gA(8, 128);
  gemm_mfma_kernel<false><<<gA, 256, 0, stream>>>(lefts, Wct, 1048576LL, tmpA,
                                                  tmpA, browp, browp);

  dim3 g3(2, 2, 64);
  gemmnt_mfma_kernel<<<g3, 256, 0, stream>>>(tmpA, rights, scoresP, tmpb,
                                             bbil);

  cky_kernel<<<dim3(Bb), dim3(1024), 0, stream>>>(scoresP, SPp, out);
}